// Round 11
// baseline (2240.230 us; speedup 1.0000x reference)
//
#include <hip/hip_runtime.h>

#define E_NODES 62
#define TOPK 10
// conv geometry: (5,64) -> c1 5x5 -> (1,60) -> pool -> 30
//                -> c2 1x5 (64ch) -> 26 -> pool -> 13
//                -> c3 1x5 (128ch) -> 9 -> pool -> 4 (pos 8 unused)

// ---- weight reshape: w2t(160,64), w3t(320,128),
// WT4[d4][j][q] = (j<32 ? Wbn1[j][4*d4+q] : gc1w[j-32][4*d4+q])  (49152 fl)
__global__ __launch_bounds__(256) void wt_kernel(
    const float* __restrict__ w2, const float* __restrict__ w3,
    const float* __restrict__ Wbn1, const float* __restrict__ gc1w,
    float* __restrict__ w2t, float* __restrict__ w3t, float* __restrict__ wt)
{
  const int j = blockIdx.x * 256 + threadIdx.x;
  if (j < 10240) {
    const int r = j >> 6, o = j & 63;
    w2t[j] = w2[o * 160 + r];
  } else if (j < 51200) {
    const int k = j - 10240;               // < 40960
    const int r = k >> 7, o = k & 127;
    w3t[k] = w3[o * 320 + r];
  } else {
    const int k = j - 51200;               // < 49152
    const int d4 = k / 384, rem = k - d4 * 384;
    const int jj = rem >> 2, q = rem & 3;
    const int d = d4 * 4 + q;
    wt[k] = (jj < 32) ? Wbn1[jj * 512 + d] : gc1w[(jj - 32) * 512 + d];
  }
}

// async global->LDS, 16B/lane; n4 = count of float4; 512-thread stride
__device__ __forceinline__ void stage16(const float* __restrict__ g,
                                        float* l, int n4, int tid) {
  for (int i = tid; i < n4; i += 512)
    __builtin_amdgcn_global_load_lds(
        (const __attribute__((address_space(1))) void*)(g + 4 * i),
        (__attribute__((address_space(3))) void*)(l + 4 * i), 16, 0, 0);
}

// ================= fused conv chain + GP tail =================
// 512 threads / block, 8 images (wave = image). Writes GP (31744,96).
// LDS floats (19968 = 79872 B -> 2 blocks/CU):
//   h1[8][32][30]@0 (7680) | h2[8][64][14]@7680 (7168) | wA@14848(2560) wB@17408(2560)
//   aliases: img[8][320] -> wA; conv1 w+b (832) -> h2 zone; GP tail:
//   WT 64-d slices (6144 fl) dbuf h1-zone/h2-zone; h3[8][512] -> wA+wB.
// __launch_bounds__(512,4): VGPR cap 128 (natural ~84 -> no spill).
__global__ __launch_bounds__(512, 4) void conv_chain_kernel(
    const float* __restrict__ x,
    const float* __restrict__ w1, const float* __restrict__ b1,
    const float* __restrict__ w2t, const float* __restrict__ b2,
    const float* __restrict__ w3t, const float* __restrict__ b3,
    const float* __restrict__ WT, float* __restrict__ GP)
{
  extern __shared__ float sm[];
  float* s_h1  = sm;            // [8][32][30] pitch 30 (rows 8B-aligned)
  float* s_h2  = sm + 7680;     // [8][64][14] pitch 14 (rows 8B-aligned)
  float* s_wa  = sm + 14848;    // 2560
  float* s_wb  = sm + 17408;    // 2560
  float* s_img = sm + 14848;    // [8][320] aliases wA
  float* s_w1  = sm + 7680;     // conv1 w(800)+b(32) aliases h2 zone
  float* s_h3  = sm + 14848;    // [8][512] aliases wA+wB (GP tail)

  const int tid = threadIdx.x;
  const int n0 = blockIdx.x * 8;
  const int im = tid >> 6;
  const int lane = tid & 63;

  stage16(x + (size_t)n0 * 320, s_img, 640, tid);
  for (int i = tid; i < 832; i += 512) s_w1[i] = (i < 800) ? w1[i] : b1[i - 800];
  __syncthreads();

  // stage conv2 chunk 0 -> wB during conv1 compute (img in wA, w1 in h2 zone)
  stage16(w2t, s_wb, 640, tid);

  // ---- conv1 + relu + pool. lane = (half, tp): stride-1 writes;
  // half0/half1 same-tp alias is 2-way (480 % 32 == 0) = free.
  {
    const int tp = lane & 31;        // pooled position, 0..29 used
    const int half = lane >> 5;      // output-channel half
    if (tp < 30) {
      const float* ib = s_img + im * 320;
      const int t0 = 2 * tp;
      float r[5][6];
#pragma unroll
      for (int kr = 0; kr < 5; ++kr)
#pragma unroll
        for (int c = 0; c < 6; ++c) r[kr][c] = ib[kr * 64 + t0 + c];
#pragma unroll 4
      for (int oi = 0; oi < 16; ++oi) {
        const int o = half * 16 + oi;
        const float* w = s_w1 + o * 25;       // 2-address broadcast reads
        float s0 = s_w1[800 + o], s1 = s0;
#pragma unroll
        for (int kr = 0; kr < 5; ++kr) {
#pragma unroll
          for (int k = 0; k < 5; ++k) {       // pure v_fmac form
            const float wv = w[kr * 5 + k];
            s0 += r[kr][k] * wv;
            s1 += r[kr][k + 1] * wv;
          }
        }
        s_h1[im * 960 + o * 30 + tp] = fmaxf(fmaxf(s0, s1), 0.f);
      }
    }
  }
  __syncthreads();   // h1 ready; conv2 chunk0 staged (vmcnt drained)

  // ---- conv2 + relu + pool: thread = (im, o). T-TILED (7+6) for reg pressure.
  {
    const int o = lane;
    const float bia = b2[o];

    // tile 0: pooled t = 0..6 (inputs 0..17)
    {
      float acc0[7], acc1[7];
#pragma unroll
      for (int t = 0; t < 7; ++t) { acc0[t] = bia; acc1[t] = bia; }
#pragma unroll 1
      for (int c = 0; c < 4; ++c) {
        const float* rb = (c & 1) ? s_wa : s_wb;
        float*       nb = (c & 1) ? s_wb : s_wa;
        stage16(w2t + ((c < 3) ? (c + 1) * 2560 : 0), nb, 640, tid);
#pragma unroll 4
        for (int cl = 0; cl < 8; ++cl) {
          const float* hr = s_h1 + im * 960 + (c * 8 + cl) * 30;  // broadcast
          float r[18];
#pragma unroll
          for (int q = 0; q < 9; ++q) {                 // 8B-aligned float2
            const float2 v = *(const float2*)(hr + 2 * q);
            r[2 * q] = v.x; r[2 * q + 1] = v.y;
          }
          const float* wb = rb + cl * 320 + o;          // (cl*5+k)*64+o, imm offsets
#pragma unroll
          for (int k = 0; k < 5; ++k) {
            const float wv = wb[k * 64];
#pragma unroll
            for (int t = 0; t < 7; ++t) {               // pure v_fmac
              acc0[t] += r[2 * t + k] * wv;
              acc1[t] += r[2 * t + 1 + k] * wv;
            }
          }
        }
        __syncthreads();    // next chunk staged + all reads of rb done
      }
#pragma unroll
      for (int t = 0; t < 7; ++t)
        s_h2[im * 896 + o * 14 + t] = fmaxf(fmaxf(acc0[t], acc1[t]), 0.f);
    }

    // tile 1: pooled t = 7..12 (inputs 14..29; r[j] = input[12+j])
    {
      float acc0[6], acc1[6];
#pragma unroll
      for (int t = 0; t < 6; ++t) { acc0[t] = bia; acc1[t] = bia; }
#pragma unroll 1
      for (int c = 0; c < 4; ++c) {
        const float* rb = (c & 1) ? s_wa : s_wb;
        float*       nb = (c & 1) ? s_wb : s_wa;
        // next: tile1 chunk c+1, else conv3 chunk 0
        stage16((c < 3) ? (w2t + (c + 1) * 2560) : w3t, nb, 640, tid);
#pragma unroll 4
        for (int cl = 0; cl < 8; ++cl) {
          const float* hr = s_h1 + im * 960 + (c * 8 + cl) * 30;
          float r[18];
#pragma unroll
          for (int q = 0; q < 9; ++q) {                 // hr+12 stays 8B-aligned
            const float2 v = *(const float2*)(hr + 12 + 2 * q);
            r[2 * q] = v.x; r[2 * q + 1] = v.y;
          }
          const float* wb = rb + cl * 320 + o;
#pragma unroll
          for (int k = 0; k < 5; ++k) {
            const float wv = wb[k * 64];
#pragma unroll
            for (int t = 0; t < 6; ++t) {
              const int t0 = 2 * t + 2;                 // input[2(t+7)] local
              acc0[t] += r[t0 + k] * wv;
              acc1[t] += r[t0 + 1 + k] * wv;
            }
          }
        }
        __syncthreads();
      }
#pragma unroll
      for (int t = 0; t < 6; ++t)
        s_h2[im * 896 + o * 14 + 7 + t] = fmaxf(fmaxf(acc0[t], acc1[t]), 0.f);
    }
  }

  // stage WT slice 0 (6144 fl <= 7680 h1 zone); h1 dead after conv2.
  stage16(WT, s_h1, 1536, tid);

  // ---- conv3 + relu + pool. 2-oc register tile (oc = lane, lane+64).
  {
    const int oc = lane;
    float acc[2][8];
#pragma unroll
    for (int t = 0; t < 8; ++t) {
      acc[0][t] = b3[oc];
      acc[1][t] = b3[64 + oc];
    }
#pragma unroll 1
    for (int k = 0; k < 16; ++k) {
      const float* rb = (k & 1) ? s_wa : s_wb;
      float*       nb = (k & 1) ? s_wb : s_wa;
      if (k < 15) stage16(w3t + (k + 1) * 2560, nb, 640, tid);
#pragma unroll 2
      for (int cl = 0; cl < 4; ++cl) {
        const float* hr = s_h2 + im * 896 + (k * 4 + cl) * 14;  // broadcast
        float r[12];
#pragma unroll
        for (int q = 0; q < 6; ++q) {                   // 8B-aligned float2
          const float2 v = *(const float2*)(hr + 2 * q);
          r[2 * q] = v.x; r[2 * q + 1] = v.y;
        }
        const float* wb = rb + cl * 640 + oc;           // (cl*5+kk)*128+oc
#pragma unroll
        for (int kk = 0; kk < 5; ++kk) {
          const float wv0 = wb[kk * 128];
          const float wv1 = wb[kk * 128 + 64];
#pragma unroll
          for (int t = 0; t < 8; ++t) {                 // pure v_fmac
            acc[0][t] += r[t + kk] * wv0;
            acc[1][t] += r[t + kk] * wv1;
          }
        }
      }
      __syncthreads();
    }
    // pooled h3 (512/image) -> wA+wB zone (all weight reads done)
    float* h3w = s_h3 + im * 512;
    float4 ov;
    ov.x = fmaxf(fmaxf(acc[0][0], acc[0][1]), 0.f);
    ov.y = fmaxf(fmaxf(acc[0][2], acc[0][3]), 0.f);
    ov.z = fmaxf(fmaxf(acc[0][4], acc[0][5]), 0.f);
    ov.w = fmaxf(fmaxf(acc[0][6], acc[0][7]), 0.f);
    *(float4*)(h3w + oc * 4) = ov;
    ov.x = fmaxf(fmaxf(acc[1][0], acc[1][1]), 0.f);
    ov.y = fmaxf(fmaxf(acc[1][2], acc[1][3]), 0.f);
    ov.z = fmaxf(fmaxf(acc[1][4], acc[1][5]), 0.f);
    ov.w = fmaxf(fmaxf(acc[1][6], acc[1][7]), 0.f);
    *(float4*)(h3w + 256 + oc * 4) = ov;
  }

  // ---- GP tail: gp[j<32] = tanh(Wbn1.h), gp[32+o] = gc1w[o].h
  // 8 slices of 64 d (6144 fl); zone (s&1 ? h2 : h1); stage s+2 into zone
  // freed at barrier s. All reads ds_read_b128.
  {
    stage16(WT + 6144, s_h2, 1536, tid);   // slice 1 (h2 dead post-conv3)
    __syncthreads();                       // h3 visible; slices 0,1 drained
    const float* h3 = s_h3 + im * 512;
    const int jP = 32 + lane, jG = lane & 31;
    float accp = 0.f, accg = 0.f;
#pragma unroll 1
    for (int s = 0; s < 8; ++s) {
      const float* z = (s & 1) ? s_h2 : s_h1;
#pragma unroll
      for (int d4 = 0; d4 < 16; ++d4) {
        const float4 hv = *(const float4*)(h3 + s * 64 + d4 * 4);   // broadcast
        const float4 wp = *(const float4*)(z + d4 * 384 + jP * 4);  // b128
        const float4 wg = *(const float4*)(z + d4 * 384 + jG * 4);  // b128
        accp += hv.x * wp.x + hv.y * wp.y + hv.z * wp.z + hv.w * wp.w;
        accg += hv.x * wg.x + hv.y * wg.y + hv.z * wg.z + hv.w * wg.w;
      }
      __syncthreads();                               // zone reads done
      if (s < 6) stage16(WT + (s + 2) * 6144, (s & 1) ? s_h2 : s_h1, 1536, tid);
    }
    float* gpo = GP + (size_t)(n0 + im) * 96;
    gpo[32 + lane] = accp;
    if (lane < 32) gpo[lane] = 1.f - 2.f / (__expf(2.f * accg) + 1.f);
  }
}

// ================= fused SOGC x3 + classifier =================
// One block (256 thr) per batch element b. (verified round 10)
__global__ __launch_bounds__(256) void sogc_fused_kernel(
    const float* __restrict__ GP,   const float* __restrict__ gc1b,
    const float* __restrict__ Wbn2, const float* __restrict__ gc2w,
    const float* __restrict__ gc2b,
    const float* __restrict__ Wbn3, const float* __restrict__ gc3w,
    const float* __restrict__ gc3b,
    const float* __restrict__ cw,   const float* __restrict__ cb,
    float* __restrict__ out)
{
  extern __shared__ float sm[];
  float* sH  = sm;                 // 62*65 = 4030
  float* sWt = sm + 4030;          // 64*97 = 6208
  float* sG  = sm + 10238;         // 62*33 = 2046
  float* sP  = sm + 12284;         // 62*64 = 3968
  float* stv = sm + 16252;         // 620
  int*   sti = (int*)(sm + 16872); // 620
  float* sred = sm + 17492;        // 16

  const int b = blockIdx.x, tid = threadIdx.x;
  const int lane = tid & 63, wave = tid >> 6;

  const float* gp = GP + (size_t)b * 62 * 96;
  for (int i = tid; i < 62 * 96; i += 256) {
    const int e = i / 96, q = i - e * 96;
    const float v = gp[i];
    if (q < 32) sG[e * 33 + q] = v; else sP[e * 64 + (q - 32)] = v;
  }
  for (int i = tid; i < 64 * 64; i += 256)        // gc2w (o,d) -> sWt[d][o]
    sWt[(i & 63) * 97 + (i >> 6)] = gc2w[i];
  for (int i = tid; i < 32 * 64; i += 256)        // Wbn2 (k,d) -> sWt[d][64+k]
    sWt[(i & 63) * 97 + 64 + (i >> 6)] = Wbn2[i];
  __syncthreads();

#define TOPK_PHASE()                                                          \
  for (int e = wave; e < E_NODES; e += 4) {                                   \
    float sc = -1e30f;                                                        \
    if (lane < E_NODES) {                                                     \
      float s = 0.f;                                                          \
      _Pragma("unroll")                                                       \
      for (int k = 0; k < 32; ++k) s += sG[e * 33 + k] * sG[lane * 33 + k];   \
      sc = s;                                                                 \
    }                                                                         \
    float mx = sc;                                                            \
    _Pragma("unroll")                                                         \
    for (int off = 32; off; off >>= 1) mx = fmaxf(mx, __shfl_xor(mx, off));   \
    float p = (lane < E_NODES) ? __expf(sc - mx) : 0.f;                       \
    float sum = p;                                                            \
    _Pragma("unroll")                                                         \
    for (int off = 32; off; off >>= 1) sum += __shfl_xor(sum, off);           \
    p = p / sum;                                                              \
    float v = (lane < E_NODES) ? p : -1.f;                                    \
    _Pragma("unroll 1")                                                       \
    for (int it = 0; it < TOPK; ++it) {                                       \
      float bv = v; int bi = lane;                                            \
      _Pragma("unroll")                                                       \
      for (int off = 32; off; off >>= 1) {                                    \
        const float ov = __shfl_xor(bv, off);                                 \
        const int   oi = __shfl_xor(bi, off);                                 \
        if (ov > bv || (ov == bv && oi < bi)) { bv = ov; bi = oi; }           \
      }                                                                       \
      if (lane == 0) { stv[e * 10 + it] = bv; sti[e * 10 + it] = bi; }        \
      if (lane == bi) v = -1.f;                                               \
    }                                                                         \
  }

#define GP_PHASE()                                                            \
  for (int e = wave; e < E_NODES; e += 4) {                                   \
    const float* hrow = sH + e * 65;                                          \
    const float* wp = sWt + lane;                                             \
    const float* wg = sWt + 64 + (lane & 31);                                 \
    float accp = 0.f, accg = 0.f;                                             \
    _Pragma("unroll 8")                                                       \
    for (int d = 0; d < 64; ++d) {                                            \
      const float h = hrow[d];                                                \
      accp += h * wp[d * 97];                                                 \
      accg += h * wg[d * 97];                                                 \
    }                                                                         \
    sP[e * 64 + lane] = accp;                                                 \
    if (lane < 32) sG[e * 33 + lane] = 1.f - 2.f / (__expf(2.f * accg) + 1.f);\
  }

  // ---- layer 1: topk + combine -> sH
  TOPK_PHASE();
  __syncthreads();
  for (int e = wave; e < E_NODES; e += 4) {
    float acc = gc1b[lane];
#pragma unroll
    for (int j = 0; j < TOPK; ++j)
      acc += stv[e * 10 + j] * sP[sti[e * 10 + j] * 64 + lane];
    sH[e * 65 + lane] = fmaxf(acc, 0.f);
  }
  __syncthreads();

  // ---- layer 2
  GP_PHASE();
  __syncthreads();
  for (int i = tid; i < 64 * 64; i += 256)
    sWt[(i & 63) * 97 + (i >> 6)] = gc3w[i];
  for (int i = tid; i < 32 * 64; i += 256)
    sWt[(i & 63) * 97 + 64 + (i >> 6)] = Wbn3[i];
  TOPK_PHASE();
  __syncthreads();
  for (int e = wave; e < E_NODES; e += 4) {
    float acc = gc2b[lane];
#pragma unroll
    for (int j = 0; j < TOPK; ++j)
      acc += stv[e * 10 + j] * sP[sti[e * 10 + j] * 64 + lane];
    sH[e * 65 + lane] = fmaxf(acc, 0.f);
  }
  __syncthreads();

  // ---- layer 3 + cls
  GP_PHASE();
  __syncthreads();
  TOPK_PHASE();
  __syncthreads();
  {
    float accn[4] = {0.f, 0.f, 0.f, 0.f};
    for (int e = wave; e < E_NODES; e += 4) {
      float acc = gc3b[lane];
#pragma unroll
      for (int j = 0; j < TOPK; ++j)
        acc += stv[e * 10 + j] * sP[sti[e * 10 + j] * 64 + lane];
      acc = fmaxf(acc, 0.f);
#pragma unroll
      for (int n = 0; n < 4; ++n)
        accn[n] += acc * cw[n * 3968 + e * 64 + lane];
    }
#pragma unroll
    for (int n = 0; n < 4; ++n) {
      float s = accn[n];
#pragma unroll
      for (int off = 32; off; off >>= 1) s += __shfl_xor(s, off);
      if (lane == 0) sred[wave * 4 + n] = s;
    }
    __syncthreads();
    if (tid < 4)
      out[b * 4 + tid] = cb[tid] + sred[tid] + sred[4 + tid] + sred[8 + tid] + sred[12 + tid];
  }
#undef TOPK_PHASE
#undef GP_PHASE
}

// ================= launch =================
extern "C" void kernel_launch(void* const* d_in, const int* in_sizes, int n_in,
                              void* d_out, int out_size, void* d_ws, size_t ws_size,
                              hipStream_t stream) {
  const float* x    = (const float*)d_in[0];
  const float* c1w  = (const float*)d_in[1];
  const float* c1b  = (const float*)d_in[2];
  const float* c2w  = (const float*)d_in[3];
  const float* c2b  = (const float*)d_in[4];
  const float* c3w  = (const float*)d_in[5];
  const float* c3b  = (const float*)d_in[6];
  const float* Wbn1 = (const float*)d_in[7];
  const float* gc1w = (const float*)d_in[8];
  const float* gc1b = (const float*)d_in[9];
  const float* Wbn2 = (const float*)d_in[10];
  const float* gc2w = (const float*)d_in[11];
  const float* gc2b = (const float*)d_in[12];
  const float* Wbn3 = (const float*)d_in[13];
  const float* gc3w = (const float*)d_in[14];
  const float* gc3b = (const float*)d_in[15];
  const float* clsw = (const float*)d_in[16];
  const float* clsb = (const float*)d_in[17];
  float* out = (float*)d_out;

  float* wsf = (float*)d_ws;
  float* W2T = wsf;                         // 10240
  float* W3T = wsf + 10240;                 // 40960
  float* WT  = wsf + 51200;                 // 49152 (WT4 layout)
  float* GP  = wsf + 100352;                // 31744*96 = 3,047,424 (~12.6 MB)

  const int CONV_BYTES = 19968 * 4;         // 79,872 B dynamic LDS (2 blocks/CU)
  const int SOGC_BYTES = 17508 * 4;         // 70,032 B dynamic LDS

  (void)hipFuncSetAttribute((const void*)conv_chain_kernel,
                            hipFuncAttributeMaxDynamicSharedMemorySize, CONV_BYTES);
  (void)hipFuncSetAttribute((const void*)sogc_fused_kernel,
                            hipFuncAttributeMaxDynamicSharedMemorySize, SOGC_BYTES);

  wt_kernel<<<392, 256, 0, stream>>>(c2w, c3w, Wbn1, gc1w, W2T, W3T, WT);
  conv_chain_kernel<<<3968, 512, CONV_BYTES, stream>>>(
      x, c1w, c1b, W2T, c2b, W3T, c3b, WT, GP);
  sogc_fused_kernel<<<512, 256, SOGC_BYTES, stream>>>(
      GP, gc1b, Wbn2, gc2w, gc2b, Wbn3, gc3w, gc3b, clsw, clsb, out);
}

// Round 12
// 1376.814 us; speedup vs baseline: 1.6271x; 1.6271x over previous
//
#include <hip/hip_runtime.h>

#define E_NODES 62
#define TOPK 10
// conv geometry: (5,64) -> c1 5x5 -> (1,60) -> pool -> 30
//                -> c2 1x5 (64ch) -> 26 -> pool -> 13
//                -> c3 1x5 (128ch) -> 9 -> pool -> 4 (pos 8 unused)

// ---- weight reshape: w2t(160,64), w3t(320,128),
// WT4[d4][j][q] = (j<32 ? Wbn1[j][4*d4+q] : gc1w[j-32][4*d4+q])  (49152 fl)
__global__ __launch_bounds__(256) void wt_kernel(
    const float* __restrict__ w2, const float* __restrict__ w3,
    const float* __restrict__ Wbn1, const float* __restrict__ gc1w,
    float* __restrict__ w2t, float* __restrict__ w3t, float* __restrict__ wt)
{
  const int j = blockIdx.x * 256 + threadIdx.x;
  if (j < 10240) {
    const int r = j >> 6, o = j & 63;
    w2t[j] = w2[o * 160 + r];
  } else if (j < 51200) {
    const int k = j - 10240;               // < 40960
    const int r = k >> 7, o = k & 127;
    w3t[k] = w3[o * 320 + r];
  } else {
    const int k = j - 51200;               // < 49152
    const int d4 = k / 384, rem = k - d4 * 384;
    const int jj = rem >> 2, q = rem & 3;
    const int d = d4 * 4 + q;
    wt[k] = (jj < 32) ? Wbn1[jj * 512 + d] : gc1w[(jj - 32) * 512 + d];
  }
}

// async global->LDS, 16B/lane; n4 = count of float4; 512-thread stride
__device__ __forceinline__ void stage16(const float* __restrict__ g,
                                        float* l, int n4, int tid) {
  for (int i = tid; i < n4; i += 512)
    __builtin_amdgcn_global_load_lds(
        (const __attribute__((address_space(1))) void*)(g + 4 * i),
        (__attribute__((address_space(3))) void*)(l + 4 * i), 16, 0, 0);
}

// ================= fused conv chain + GP tail =================
// 512 threads / block, 8 images (wave = image). Writes GP (31744,96).
// LDS floats (19968 = 79872 B -> 2 blocks/CU):
//   h1[8][32][30]@0 (7680) | h2[8][64][14]@7680 (7168) | wA@14848(2560) wB@17408(2560)
//   aliases: img[8][320] -> wA; conv1 w+b (832) -> h2 zone; GP tail:
//   WT 64-d slices (6144 fl) dbuf h1-zone/h2-zone; h3[8][512] -> wA+wB.
// __launch_bounds__(512,2): EMPIRICAL semantics (round 11): 2nd arg acts as
// workgroups/CU on this toolchain. (512,4) -> 32 waves/CU -> 64-VGPR cap ->
// 5 GB spill. (512,2) -> 16 waves/CU -> 128-VGPR cap; natural ~84 fits.
__global__ __launch_bounds__(512, 2) void conv_chain_kernel(
    const float* __restrict__ x,
    const float* __restrict__ w1, const float* __restrict__ b1,
    const float* __restrict__ w2t, const float* __restrict__ b2,
    const float* __restrict__ w3t, const float* __restrict__ b3,
    const float* __restrict__ WT, float* __restrict__ GP)
{
  extern __shared__ float sm[];
  float* s_h1  = sm;            // [8][32][30] pitch 30 (rows 8B-aligned)
  float* s_h2  = sm + 7680;     // [8][64][14] pitch 14 (rows 8B-aligned)
  float* s_wa  = sm + 14848;    // 2560
  float* s_wb  = sm + 17408;    // 2560
  float* s_img = sm + 14848;    // [8][320] aliases wA
  float* s_w1  = sm + 7680;     // conv1 w(800)+b(32) aliases h2 zone
  float* s_h3  = sm + 14848;    // [8][512] aliases wA+wB (GP tail)

  const int tid = threadIdx.x;
  const int n0 = blockIdx.x * 8;
  const int im = tid >> 6;
  const int lane = tid & 63;

  stage16(x + (size_t)n0 * 320, s_img, 640, tid);
  for (int i = tid; i < 832; i += 512) s_w1[i] = (i < 800) ? w1[i] : b1[i - 800];
  __syncthreads();

  // stage conv2 chunk 0 -> wB during conv1 compute (img in wA, w1 in h2 zone)
  stage16(w2t, s_wb, 640, tid);

  // ---- conv1 + relu + pool. lane = (half, tp): stride-1 writes;
  // half0/half1 same-tp alias is 2-way (480 % 32 == 0) = free.
  {
    const int tp = lane & 31;        // pooled position, 0..29 used
    const int half = lane >> 5;      // output-channel half
    if (tp < 30) {
      const float* ib = s_img + im * 320;
      const int t0 = 2 * tp;
      float r[5][6];
#pragma unroll
      for (int kr = 0; kr < 5; ++kr)
#pragma unroll
        for (int c = 0; c < 6; ++c) r[kr][c] = ib[kr * 64 + t0 + c];
#pragma unroll 4
      for (int oi = 0; oi < 16; ++oi) {
        const int o = half * 16 + oi;
        const float* w = s_w1 + o * 25;       // 2-address broadcast reads
        float s0 = s_w1[800 + o], s1 = s0;
#pragma unroll
        for (int kr = 0; kr < 5; ++kr) {
#pragma unroll
          for (int k = 0; k < 5; ++k) {       // pure v_fmac form
            const float wv = w[kr * 5 + k];
            s0 += r[kr][k] * wv;
            s1 += r[kr][k + 1] * wv;
          }
        }
        s_h1[im * 960 + o * 30 + tp] = fmaxf(fmaxf(s0, s1), 0.f);
      }
    }
  }
  __syncthreads();   // h1 ready; conv2 chunk0 staged (vmcnt drained)

  // ---- conv2 + relu + pool: thread = (im, o). T-TILED (7+6) for reg pressure.
  {
    const int o = lane;
    const float bia = b2[o];

    // tile 0: pooled t = 0..6 (inputs 0..17)
    {
      float acc0[7], acc1[7];
#pragma unroll
      for (int t = 0; t < 7; ++t) { acc0[t] = bia; acc1[t] = bia; }
#pragma unroll 1
      for (int c = 0; c < 4; ++c) {
        const float* rb = (c & 1) ? s_wa : s_wb;
        float*       nb = (c & 1) ? s_wb : s_wa;
        stage16(w2t + ((c < 3) ? (c + 1) * 2560 : 0), nb, 640, tid);
#pragma unroll 4
        for (int cl = 0; cl < 8; ++cl) {
          const float* hr = s_h1 + im * 960 + (c * 8 + cl) * 30;  // broadcast
          float r[18];
#pragma unroll
          for (int q = 0; q < 9; ++q) {                 // 8B-aligned float2
            const float2 v = *(const float2*)(hr + 2 * q);
            r[2 * q] = v.x; r[2 * q + 1] = v.y;
          }
          const float* wb = rb + cl * 320 + o;          // (cl*5+k)*64+o, imm offsets
#pragma unroll
          for (int k = 0; k < 5; ++k) {
            const float wv = wb[k * 64];
#pragma unroll
            for (int t = 0; t < 7; ++t) {               // pure v_fmac
              acc0[t] += r[2 * t + k] * wv;
              acc1[t] += r[2 * t + 1 + k] * wv;
            }
          }
        }
        __syncthreads();    // next chunk staged + all reads of rb done
      }
#pragma unroll
      for (int t = 0; t < 7; ++t)
        s_h2[im * 896 + o * 14 + t] = fmaxf(fmaxf(acc0[t], acc1[t]), 0.f);
    }

    // tile 1: pooled t = 7..12 (inputs 14..29; r[j] = input[12+j])
    {
      float acc0[6], acc1[6];
#pragma unroll
      for (int t = 0; t < 6; ++t) { acc0[t] = bia; acc1[t] = bia; }
#pragma unroll 1
      for (int c = 0; c < 4; ++c) {
        const float* rb = (c & 1) ? s_wa : s_wb;
        float*       nb = (c & 1) ? s_wb : s_wa;
        // next: tile1 chunk c+1, else conv3 chunk 0
        stage16((c < 3) ? (w2t + (c + 1) * 2560) : w3t, nb, 640, tid);
#pragma unroll 4
        for (int cl = 0; cl < 8; ++cl) {
          const float* hr = s_h1 + im * 960 + (c * 8 + cl) * 30;
          float r[18];
#pragma unroll
          for (int q = 0; q < 9; ++q) {                 // hr+12 stays 8B-aligned
            const float2 v = *(const float2*)(hr + 12 + 2 * q);
            r[2 * q] = v.x; r[2 * q + 1] = v.y;
          }
          const float* wb = rb + cl * 320 + o;
#pragma unroll
          for (int k = 0; k < 5; ++k) {
            const float wv = wb[k * 64];
#pragma unroll
            for (int t = 0; t < 6; ++t) {
              const int t0 = 2 * t + 2;                 // input[2(t+7)] local
              acc0[t] += r[t0 + k] * wv;
              acc1[t] += r[t0 + 1 + k] * wv;
            }
          }
        }
        __syncthreads();
      }
#pragma unroll
      for (int t = 0; t < 6; ++t)
        s_h2[im * 896 + o * 14 + 7 + t] = fmaxf(fmaxf(acc0[t], acc1[t]), 0.f);
    }
  }

  // stage WT slice 0 (6144 fl <= 7680 h1 zone); h1 dead after conv2.
  stage16(WT, s_h1, 1536, tid);

  // ---- conv3 + relu + pool. 2-oc register tile (oc = lane, lane+64).
  {
    const int oc = lane;
    float acc[2][8];
#pragma unroll
    for (int t = 0; t < 8; ++t) {
      acc[0][t] = b3[oc];
      acc[1][t] = b3[64 + oc];
    }
#pragma unroll 1
    for (int k = 0; k < 16; ++k) {
      const float* rb = (k & 1) ? s_wa : s_wb;
      float*       nb = (k & 1) ? s_wb : s_wa;
      if (k < 15) stage16(w3t + (k + 1) * 2560, nb, 640, tid);
#pragma unroll 2
      for (int cl = 0; cl < 4; ++cl) {
        const float* hr = s_h2 + im * 896 + (k * 4 + cl) * 14;  // broadcast
        float r[12];
#pragma unroll
        for (int q = 0; q < 6; ++q) {                   // 8B-aligned float2
          const float2 v = *(const float2*)(hr + 2 * q);
          r[2 * q] = v.x; r[2 * q + 1] = v.y;
        }
        const float* wb = rb + cl * 640 + oc;           // (cl*5+kk)*128+oc
#pragma unroll
        for (int kk = 0; kk < 5; ++kk) {
          const float wv0 = wb[kk * 128];
          const float wv1 = wb[kk * 128 + 64];
#pragma unroll
          for (int t = 0; t < 8; ++t) {                 // pure v_fmac
            acc[0][t] += r[t + kk] * wv0;
            acc[1][t] += r[t + kk] * wv1;
          }
        }
      }
      __syncthreads();
    }
    // pooled h3 (512/image) -> wA+wB zone (all weight reads done)
    float* h3w = s_h3 + im * 512;
    float4 ov;
    ov.x = fmaxf(fmaxf(acc[0][0], acc[0][1]), 0.f);
    ov.y = fmaxf(fmaxf(acc[0][2], acc[0][3]), 0.f);
    ov.z = fmaxf(fmaxf(acc[0][4], acc[0][5]), 0.f);
    ov.w = fmaxf(fmaxf(acc[0][6], acc[0][7]), 0.f);
    *(float4*)(h3w + oc * 4) = ov;
    ov.x = fmaxf(fmaxf(acc[1][0], acc[1][1]), 0.f);
    ov.y = fmaxf(fmaxf(acc[1][2], acc[1][3]), 0.f);
    ov.z = fmaxf(fmaxf(acc[1][4], acc[1][5]), 0.f);
    ov.w = fmaxf(fmaxf(acc[1][6], acc[1][7]), 0.f);
    *(float4*)(h3w + 256 + oc * 4) = ov;
  }

  // ---- GP tail: gp[j<32] = tanh(Wbn1.h), gp[32+o] = gc1w[o].h
  // 8 slices of 64 d (6144 fl); zone (s&1 ? h2 : h1); stage s+2 into zone
  // freed at barrier s. All reads ds_read_b128.
  {
    stage16(WT + 6144, s_h2, 1536, tid);   // slice 1 (h2 dead post-conv3)
    __syncthreads();                       // h3 visible; slices 0,1 drained
    const float* h3 = s_h3 + im * 512;
    const int jP = 32 + lane, jG = lane & 31;
    float accp = 0.f, accg = 0.f;
#pragma unroll 1
    for (int s = 0; s < 8; ++s) {
      const float* z = (s & 1) ? s_h2 : s_h1;
#pragma unroll
      for (int d4 = 0; d4 < 16; ++d4) {
        const float4 hv = *(const float4*)(h3 + s * 64 + d4 * 4);   // broadcast
        const float4 wp = *(const float4*)(z + d4 * 384 + jP * 4);  // b128
        const float4 wg = *(const float4*)(z + d4 * 384 + jG * 4);  // b128
        accp += hv.x * wp.x + hv.y * wp.y + hv.z * wp.z + hv.w * wp.w;
        accg += hv.x * wg.x + hv.y * wg.y + hv.z * wg.z + hv.w * wg.w;
      }
      __syncthreads();                               // zone reads done
      if (s < 6) stage16(WT + (s + 2) * 6144, (s & 1) ? s_h2 : s_h1, 1536, tid);
    }
    float* gpo = GP + (size_t)(n0 + im) * 96;
    gpo[32 + lane] = accp;
    if (lane < 32) gpo[lane] = 1.f - 2.f / (__expf(2.f * accg) + 1.f);
  }
}

// ================= fused SOGC x3 + classifier =================
// One block (256 thr) per batch element b. (verified round 10)
__global__ __launch_bounds__(256) void sogc_fused_kernel(
    const float* __restrict__ GP,   const float* __restrict__ gc1b,
    const float* __restrict__ Wbn2, const float* __restrict__ gc2w,
    const float* __restrict__ gc2b,
    const float* __restrict__ Wbn3, const float* __restrict__ gc3w,
    const float* __restrict__ gc3b,
    const float* __restrict__ cw,   const float* __restrict__ cb,
    float* __restrict__ out)
{
  extern __shared__ float sm[];
  float* sH  = sm;                 // 62*65 = 4030
  float* sWt = sm + 4030;          // 64*97 = 6208
  float* sG  = sm + 10238;         // 62*33 = 2046
  float* sP  = sm + 12284;         // 62*64 = 3968
  float* stv = sm + 16252;         // 620
  int*   sti = (int*)(sm + 16872); // 620
  float* sred = sm + 17492;        // 16

  const int b = blockIdx.x, tid = threadIdx.x;
  const int lane = tid & 63, wave = tid >> 6;

  const float* gp = GP + (size_t)b * 62 * 96;
  for (int i = tid; i < 62 * 96; i += 256) {
    const int e = i / 96, q = i - e * 96;
    const float v = gp[i];
    if (q < 32) sG[e * 33 + q] = v; else sP[e * 64 + (q - 32)] = v;
  }
  for (int i = tid; i < 64 * 64; i += 256)        // gc2w (o,d) -> sWt[d][o]
    sWt[(i & 63) * 97 + (i >> 6)] = gc2w[i];
  for (int i = tid; i < 32 * 64; i += 256)        // Wbn2 (k,d) -> sWt[d][64+k]
    sWt[(i & 63) * 97 + 64 + (i >> 6)] = Wbn2[i];
  __syncthreads();

#define TOPK_PHASE()                                                          \
  for (int e = wave; e < E_NODES; e += 4) {                                   \
    float sc = -1e30f;                                                        \
    if (lane < E_NODES) {                                                     \
      float s = 0.f;                                                          \
      _Pragma("unroll")                                                       \
      for (int k = 0; k < 32; ++k) s += sG[e * 33 + k] * sG[lane * 33 + k];   \
      sc = s;                                                                 \
    }                                                                         \
    float mx = sc;                                                            \
    _Pragma("unroll")                                                         \
    for (int off = 32; off; off >>= 1) mx = fmaxf(mx, __shfl_xor(mx, off));   \
    float p = (lane < E_NODES) ? __expf(sc - mx) : 0.f;                       \
    float sum = p;                                                            \
    _Pragma("unroll")                                                         \
    for (int off = 32; off; off >>= 1) sum += __shfl_xor(sum, off);           \
    p = p / sum;                                                              \
    float v = (lane < E_NODES) ? p : -1.f;                                    \
    _Pragma("unroll 1")                                                       \
    for (int it = 0; it < TOPK; ++it) {                                       \
      float bv = v; int bi = lane;                                            \
      _Pragma("unroll")                                                       \
      for (int off = 32; off; off >>= 1) {                                    \
        const float ov = __shfl_xor(bv, off);                                 \
        const int   oi = __shfl_xor(bi, off);                                 \
        if (ov > bv || (ov == bv && oi < bi)) { bv = ov; bi = oi; }           \
      }                                                                       \
      if (lane == 0) { stv[e * 10 + it] = bv; sti[e * 10 + it] = bi; }        \
      if (lane == bi) v = -1.f;                                               \
    }                                                                         \
  }

#define GP_PHASE()                                                            \
  for (int e = wave; e < E_NODES; e += 4) {                                   \
    const float* hrow = sH + e * 65;                                          \
    const float* wp = sWt + lane;                                             \
    const float* wg = sWt + 64 + (lane & 31);                                 \
    float accp = 0.f, accg = 0.f;                                             \
    _Pragma("unroll 8")                                                       \
    for (int d = 0; d < 64; ++d) {                                            \
      const float h = hrow[d];                                                \
      accp += h * wp[d * 97];                                                 \
      accg += h * wg[d * 97];                                                 \
    }                                                                         \
    sP[e * 64 + lane] = accp;                                                 \
    if (lane < 32) sG[e * 33 + lane] = 1.f - 2.f / (__expf(2.f * accg) + 1.f);\
  }

  // ---- layer 1: topk + combine -> sH
  TOPK_PHASE();
  __syncthreads();
  for (int e = wave; e < E_NODES; e += 4) {
    float acc = gc1b[lane];
#pragma unroll
    for (int j = 0; j < TOPK; ++j)
      acc += stv[e * 10 + j] * sP[sti[e * 10 + j] * 64 + lane];
    sH[e * 65 + lane] = fmaxf(acc, 0.f);
  }
  __syncthreads();

  // ---- layer 2
  GP_PHASE();
  __syncthreads();
  for (int i = tid; i < 64 * 64; i += 256)
    sWt[(i & 63) * 97 + (i >> 6)] = gc3w[i];
  for (int i = tid; i < 32 * 64; i += 256)
    sWt[(i & 63) * 97 + 64 + (i >> 6)] = Wbn3[i];
  TOPK_PHASE();
  __syncthreads();
  for (int e = wave; e < E_NODES; e += 4) {
    float acc = gc2b[lane];
#pragma unroll
    for (int j = 0; j < TOPK; ++j)
      acc += stv[e * 10 + j] * sP[sti[e * 10 + j] * 64 + lane];
    sH[e * 65 + lane] = fmaxf(acc, 0.f);
  }
  __syncthreads();

  // ---- layer 3 + cls
  GP_PHASE();
  __syncthreads();
  TOPK_PHASE();
  __syncthreads();
  {
    float accn[4] = {0.f, 0.f, 0.f, 0.f};
    for (int e = wave; e < E_NODES; e += 4) {
      float acc = gc3b[lane];
#pragma unroll
      for (int j = 0; j < TOPK; ++j)
        acc += stv[e * 10 + j] * sP[sti[e * 10 + j] * 64 + lane];
      acc = fmaxf(acc, 0.f);
#pragma unroll
      for (int n = 0; n < 4; ++n)
        accn[n] += acc * cw[n * 3968 + e * 64 + lane];
    }
#pragma unroll
    for (int n = 0; n < 4; ++n) {
      float s = accn[n];
#pragma unroll
      for (int off = 32; off; off >>= 1) s += __shfl_xor(s, off);
      if (lane == 0) sred[wave * 4 + n] = s;
    }
    __syncthreads();
    if (tid < 4)
      out[b * 4 + tid] = cb[tid] + sred[tid] + sred[4 + tid] + sred[8 + tid] + sred[12 + tid];
  }
#undef TOPK_PHASE
#undef GP_PHASE
}

// ================= launch =================
extern "C" void kernel_launch(void* const* d_in, const int* in_sizes, int n_in,
                              void* d_out, int out_size, void* d_ws, size_t ws_size,
                              hipStream_t stream) {
  const float* x    = (const float*)d_in[0];
  const float* c1w  = (const float*)d_in[1];
  const float* c1b  = (const float*)d_in[2];
  const float* c2w  = (const float*)d_in[3];
  const float* c2b  = (const float*)d_in[4];
  const float* c3w  = (const float*)d_in[5];
  const float* c3b  = (const float*)d_in[6];
  const float* Wbn1 = (const float*)d_in[7];
  const float* gc1w = (const float*)d_in[8];
  const float* gc1b = (const float*)d_in[9];
  const float* Wbn2 = (const float*)d_in[10];
  const float* gc2w = (const float*)d_in[11];
  const float* gc2b = (const float*)d_in[12];
  const float* Wbn3 = (const float*)d_in[13];
  const float* gc3w = (const float*)d_in[14];
  const float* gc3b = (const float*)d_in[15];
  const float* clsw = (const float*)d_in[16];
  const float* clsb = (const float*)d_in[17];
  float* out = (float*)d_out;

  float* wsf = (float*)d_ws;
  float* W2T = wsf;                         // 10240
  float* W3T = wsf + 10240;                 // 40960
  float* WT  = wsf + 51200;                 // 49152 (WT4 layout)
  float* GP  = wsf + 100352;                // 31744*96 = 3,047,424 (~12.6 MB)

  const int CONV_BYTES = 19968 * 4;         // 79,872 B dynamic LDS (2 blocks/CU)
  const int SOGC_BYTES = 17508 * 4;         // 70,032 B dynamic LDS

  (void)hipFuncSetAttribute((const void*)conv_chain_kernel,
                            hipFuncAttributeMaxDynamicSharedMemorySize, CONV_BYTES);
  (void)hipFuncSetAttribute((const void*)sogc_fused_kernel,
                            hipFuncAttributeMaxDynamicSharedMemorySize, SOGC_BYTES);

  wt_kernel<<<392, 256, 0, stream>>>(c2w, c3w, Wbn1, gc1w, W2T, W3T, WT);
  conv_chain_kernel<<<3968, 512, CONV_BYTES, stream>>>(
      x, c1w, c1b, W2T, c2b, W3T, c3b, WT, GP);
  sogc_fused_kernel<<<512, 256, SOGC_BYTES, stream>>>(
      GP, gc1b, Wbn2, gc2w, gc2b, Wbn3, gc3w, gc3b, clsw, clsb, out);
}

// Round 13
// 1023.211 us; speedup vs baseline: 2.1894x; 1.3456x over previous
//
#include <hip/hip_runtime.h>

#define E_NODES 62
#define TOPK 10
// conv geometry: (5,64) -> c1 5x5 -> (1,60) -> pool -> 30
//                -> c2 1x5 (64ch) -> 26 -> pool -> 13
//                -> c3 1x5 (128ch) -> 9 -> pool -> 4 (pos 8 unused)

// ---- weight reshape: w2t(160,64), w3t(320,128),
// WT4[d4][j][q] = (j<32 ? Wbn1[j][4*d4+q] : gc1w[j-32][4*d4+q])  (49152 fl)
__global__ __launch_bounds__(256) void wt_kernel(
    const float* __restrict__ w2, const float* __restrict__ w3,
    const float* __restrict__ Wbn1, const float* __restrict__ gc1w,
    float* __restrict__ w2t, float* __restrict__ w3t, float* __restrict__ wt)
{
  const int j = blockIdx.x * 256 + threadIdx.x;
  if (j < 10240) {
    const int r = j >> 6, o = j & 63;
    w2t[j] = w2[o * 160 + r];
  } else if (j < 51200) {
    const int k = j - 10240;               // < 40960
    const int r = k >> 7, o = k & 127;
    w3t[k] = w3[o * 320 + r];
  } else {
    const int k = j - 51200;               // < 49152
    const int d4 = k / 384, rem = k - d4 * 384;
    const int jj = rem >> 2, q = rem & 3;
    const int d = d4 * 4 + q;
    wt[k] = (jj < 32) ? Wbn1[jj * 512 + d] : gc1w[(jj - 32) * 512 + d];
  }
}

// async global->LDS, 16B/lane; n4 = count of float4; 256-thread stride
__device__ __forceinline__ void stage16(const float* __restrict__ g,
                                        float* l, int n4, int tid) {
  for (int i = tid; i < n4; i += 256)
    __builtin_amdgcn_global_load_lds(
        (const __attribute__((address_space(1))) void*)(g + 4 * i),
        (__attribute__((address_space(3))) void*)(l + 4 * i), 16, 0, 0);
}

// ================= fused conv chain + GP tail =================
// EXACT round-9/10 verified kernel: 256 thr / 4 images, 890 us, VGPR 84,
// no spill, ~3 blocks/CU. Occupancy ledger (r11/r12 lessons): 512-thr
// variants hit the VGPR-residency wall (112 VGPR -> 1 block/CU); this
// 256-thr/(256,3)/53248B config is the proven optimum envelope.
__global__ __launch_bounds__(256, 3) void conv_chain_kernel(
    const float* __restrict__ x,
    const float* __restrict__ w1, const float* __restrict__ b1,
    const float* __restrict__ w2t, const float* __restrict__ b2,
    const float* __restrict__ w3t, const float* __restrict__ b3,
    const float* __restrict__ WT, float* __restrict__ GP)
{
  __shared__ float sm[13312];
  float* s_h1  = sm;            // 4*32*32 (pitch 32)
  float* s_h2  = sm + 4096;     // 4*64*16 (pitch 16)
  float* s_wa  = sm + 8192;     // 2560
  float* s_wb  = sm + 10752;    // 2560
  float* s_w1  = sm + 8192;     // conv1 w(800)+b(32), aliases wA
  float* s_img = sm + 9024;     // 1280, aliases wA

  const int tid = threadIdx.x;
  const int n0 = blockIdx.x * 4;
  const int im = tid >> 6;
  const int lane = tid & 63;

  stage16(x + (size_t)n0 * 320, s_img, 320, tid);
  for (int i = tid; i < 832; i += 256) s_w1[i] = (i < 800) ? w1[i] : b1[i - 800];
  __syncthreads();

  // stage conv2 chunk 0 -> wB during conv1 compute
  stage16(w2t, s_wb, 640, tid);

  // ---- conv1 + relu + pool. lane = (half, tp): stride-1 writes (no conflict)
  {
    const int tp = lane & 31;        // pooled position, 0..29 used
    const int half = lane >> 5;      // output-channel half
    if (tp < 30) {
      const float* ib = s_img + im * 320;
      const int t0 = 2 * tp;
      float r[5][6];
#pragma unroll
      for (int kr = 0; kr < 5; ++kr)
#pragma unroll
        for (int c = 0; c < 6; ++c) r[kr][c] = ib[kr * 64 + t0 + c];
#pragma unroll 4
      for (int oi = 0; oi < 16; ++oi) {
        const int o = half * 16 + oi;
        const float* w = s_w1 + o * 25;       // 2-address broadcast reads
        float s0 = s_w1[800 + o], s1 = s0;
#pragma unroll
        for (int kr = 0; kr < 5; ++kr) {
#pragma unroll
          for (int k = 0; k < 5; ++k) {       // pure v_fmac form
            const float wv = w[kr * 5 + k];
            s0 += r[kr][k] * wv;
            s1 += r[kr][k + 1] * wv;
          }
        }
        s_h1[im * 1024 + o * 32 + tp] = fmaxf(fmaxf(s0, s1), 0.f);
      }
    }
  }
  __syncthreads();   // h1 ready; conv2 chunk0 staged (vmcnt drained)

  // ---- conv2 + relu + pool: thread = (im, o). T-TILED (7+6) for reg pressure.
  {
    const int o = lane;
    const float bia = b2[o];

    // tile 0: pooled t = 0..6 (inputs 0..17)
    {
      float acc0[7], acc1[7];
#pragma unroll
      for (int t = 0; t < 7; ++t) { acc0[t] = bia; acc1[t] = bia; }
#pragma unroll 1
      for (int c = 0; c < 4; ++c) {
        const float* rb = (c & 1) ? s_wa : s_wb;
        float*       nb = (c & 1) ? s_wb : s_wa;
        stage16(w2t + ((c < 3) ? (c + 1) * 2560 : 0), nb, 640, tid);
#pragma unroll 4
        for (int cl = 0; cl < 8; ++cl) {
          const float* hr = s_h1 + im * 1024 + (c * 8 + cl) * 32;  // broadcast
          float r[18];
#pragma unroll
          for (int q = 0; q < 4; ++q) {
            const float4 v = *(const float4*)(hr + q * 4);
            r[q * 4] = v.x; r[q * 4 + 1] = v.y; r[q * 4 + 2] = v.z; r[q * 4 + 3] = v.w;
          }
          { const float2 v = *(const float2*)(hr + 16); r[16] = v.x; r[17] = v.y; }
          const float* wb = rb + cl * 320 + o;         // (cl*5+k)*64+o, imm offsets
#pragma unroll
          for (int k = 0; k < 5; ++k) {
            const float wv = wb[k * 64];
#pragma unroll
            for (int t = 0; t < 7; ++t) {              // pure v_fmac
              acc0[t] += r[2 * t + k] * wv;
              acc1[t] += r[2 * t + 1 + k] * wv;
            }
          }
        }
        __syncthreads();    // next chunk staged + all reads of rb done
      }
#pragma unroll
      for (int t = 0; t < 7; ++t)
        s_h2[im * 1024 + o * 16 + t] = fmaxf(fmaxf(acc0[t], acc1[t]), 0.f);
    }

    // tile 1: pooled t = 7..12 (inputs 14..29; r[j] = input[12+j])
    {
      float acc0[6], acc1[6];
#pragma unroll
      for (int t = 0; t < 6; ++t) { acc0[t] = bia; acc1[t] = bia; }
#pragma unroll 1
      for (int c = 0; c < 4; ++c) {
        const float* rb = (c & 1) ? s_wa : s_wb;
        float*       nb = (c & 1) ? s_wb : s_wa;
        // next: tile1 chunk c+1, else conv3 chunk 0
        stage16((c < 3) ? (w2t + (c + 1) * 2560) : w3t, nb, 640, tid);
#pragma unroll 4
        for (int cl = 0; cl < 8; ++cl) {
          const float* hr = s_h1 + im * 1024 + (c * 8 + cl) * 32;
          float r[18];
#pragma unroll
          for (int q = 0; q < 4; ++q) {
            const float4 v = *(const float4*)(hr + 12 + q * 4);
            r[q * 4] = v.x; r[q * 4 + 1] = v.y; r[q * 4 + 2] = v.z; r[q * 4 + 3] = v.w;
          }
          { const float2 v = *(const float2*)(hr + 28); r[16] = v.x; r[17] = v.y; }
          const float* wb = rb + cl * 320 + o;
#pragma unroll
          for (int k = 0; k < 5; ++k) {
            const float wv = wb[k * 64];
#pragma unroll
            for (int t = 0; t < 6; ++t) {
              const int t0 = 2 * t + 2;                // input[2(t+7)] local
              acc0[t] += r[t0 + k] * wv;
              acc1[t] += r[t0 + 1 + k] * wv;
            }
          }
        }
        __syncthreads();
      }
#pragma unroll
      for (int t = 0; t < 6; ++t)
        s_h2[im * 1024 + o * 16 + 7 + t] = fmaxf(fmaxf(acc0[t], acc1[t]), 0.f);
    }
  }

  // stage WT slice 0 (3072 fl <= 4096 h1 zone); h1 dead after conv2.
  stage16(WT, s_h1, 768, tid);

  // ---- conv3 + relu + pool -> pooled h3 in wB zone. 2-oc tile (lane, lane+64).
  {
    const int oc = lane;
    float acc[2][8];
#pragma unroll
    for (int t = 0; t < 8; ++t) {
      acc[0][t] = b3[oc];
      acc[1][t] = b3[64 + oc];
    }
#pragma unroll 1
    for (int k = 0; k < 16; ++k) {
      const float* rb = (k & 1) ? s_wa : s_wb;
      float*       nb = (k & 1) ? s_wb : s_wa;
      if (k < 15) stage16(w3t + (k + 1) * 2560, nb, 640, tid);
#pragma unroll 2
      for (int cl = 0; cl < 4; ++cl) {
        const float* hr = s_h2 + im * 1024 + (k * 4 + cl) * 16;  // broadcast
        float r[12];
#pragma unroll
        for (int q = 0; q < 3; ++q) {
          const float4 v = *(const float4*)(hr + q * 4);
          r[q * 4] = v.x; r[q * 4 + 1] = v.y; r[q * 4 + 2] = v.z; r[q * 4 + 3] = v.w;
        }
        const float* wb = rb + cl * 640 + oc;          // (cl*5+kk)*128+oc
#pragma unroll
        for (int kk = 0; kk < 5; ++kk) {
          const float wv0 = wb[kk * 128];
          const float wv1 = wb[kk * 128 + 64];
#pragma unroll
          for (int t = 0; t < 8; ++t) {                // pure v_fmac
            acc[0][t] += r[t + kk] * wv0;
            acc[1][t] += r[t + kk] * wv1;
          }
        }
      }
      __syncthreads();
    }
    // pooled h3 (512/image) -> wB zone (free: last wB read is k=14)
    float* h3w = s_wb + im * 520;
    float4 ov;
    ov.x = fmaxf(fmaxf(acc[0][0], acc[0][1]), 0.f);
    ov.y = fmaxf(fmaxf(acc[0][2], acc[0][3]), 0.f);
    ov.z = fmaxf(fmaxf(acc[0][4], acc[0][5]), 0.f);
    ov.w = fmaxf(fmaxf(acc[0][6], acc[0][7]), 0.f);
    *(float4*)(h3w + oc * 4) = ov;
    ov.x = fmaxf(fmaxf(acc[1][0], acc[1][1]), 0.f);
    ov.y = fmaxf(fmaxf(acc[1][2], acc[1][3]), 0.f);
    ov.z = fmaxf(fmaxf(acc[1][4], acc[1][5]), 0.f);
    ov.w = fmaxf(fmaxf(acc[1][6], acc[1][7]), 0.f);
    *(float4*)(h3w + 256 + oc * 4) = ov;
  }

  // ---- GP tail: gp[j<32] = tanh(Wbn1.h), gp[32+o] = gc1w[o].h
  // 16 slices of 32 d (3072 fl); zone (s&1 ? h2 : h1); stage s+2 into zone
  // freed at barrier s. All reads ds_read_b128.
  {
    stage16(WT + 3072, s_h2, 768, tid);    // slice 1 (h2 dead post-conv3)
    __syncthreads();                       // h3 visible; slices 0,1 drained
    const float* h3 = s_wb + im * 520;
    const int jP = 32 + lane, jG = lane & 31;
    float accp = 0.f, accg = 0.f;
#pragma unroll 1
    for (int s = 0; s < 16; ++s) {
      const float* z = (s & 1) ? s_h2 : s_h1;
#pragma unroll
      for (int d4 = 0; d4 < 8; ++d4) {
        const float4 hv = *(const float4*)(h3 + s * 32 + d4 * 4);   // broadcast
        const float4 wp = *(const float4*)(z + d4 * 384 + jP * 4);  // b128
        const float4 wg = *(const float4*)(z + d4 * 384 + jG * 4);  // b128
        accp += hv.x * wp.x + hv.y * wp.y + hv.z * wp.z + hv.w * wp.w;
        accg += hv.x * wg.x + hv.y * wg.y + hv.z * wg.z + hv.w * wg.w;
      }
      __syncthreads();                               // zone reads done
      if (s < 14) stage16(WT + (s + 2) * 3072, (s & 1) ? s_h2 : s_h1, 768, tid);
    }
    float* gpo = GP + (size_t)(n0 + im) * 96;
    gpo[32 + lane] = accp;
    if (lane < 32) gpo[lane] = 1.f - 2.f / (__expf(2.f * accg) + 1.f);
  }
}

// ================= fused SOGC x3 + classifier =================
// One block (512 thr = 8 waves) per batch element b; e-rows strided by 8
// (halves serial phase depth vs the r10 4-wave version).
__global__ __launch_bounds__(512, 2) void sogc_fused_kernel(
    const float* __restrict__ GP,   const float* __restrict__ gc1b,
    const float* __restrict__ Wbn2, const float* __restrict__ gc2w,
    const float* __restrict__ gc2b,
    const float* __restrict__ Wbn3, const float* __restrict__ gc3w,
    const float* __restrict__ gc3b,
    const float* __restrict__ cw,   const float* __restrict__ cb,
    float* __restrict__ out)
{
  extern __shared__ float sm[];
  float* sH  = sm;                 // 62*65 = 4030
  float* sWt = sm + 4030;          // 64*97 = 6208
  float* sG  = sm + 10238;         // 62*33 = 2046
  float* sP  = sm + 12284;         // 62*64 = 3968
  float* stv = sm + 16252;         // 620
  int*   sti = (int*)(sm + 16872); // 620
  float* sred = sm + 17492;        // 32 (8 waves x 4)

  const int b = blockIdx.x, tid = threadIdx.x;
  const int lane = tid & 63, wave = tid >> 6;   // wave in [0,8)

  const float* gp = GP + (size_t)b * 62 * 96;
  for (int i = tid; i < 62 * 96; i += 512) {
    const int e = i / 96, q = i - e * 96;
    const float v = gp[i];
    if (q < 32) sG[e * 33 + q] = v; else sP[e * 64 + (q - 32)] = v;
  }
  for (int i = tid; i < 64 * 64; i += 512)        // gc2w (o,d) -> sWt[d][o]
    sWt[(i & 63) * 97 + (i >> 6)] = gc2w[i];
  for (int i = tid; i < 32 * 64; i += 512)        // Wbn2 (k,d) -> sWt[d][64+k]
    sWt[(i & 63) * 97 + 64 + (i >> 6)] = Wbn2[i];
  __syncthreads();

#define TOPK_PHASE()                                                          \
  for (int e = wave; e < E_NODES; e += 8) {                                   \
    float sc = -1e30f;                                                        \
    if (lane < E_NODES) {                                                     \
      float s = 0.f;                                                          \
      _Pragma("unroll")                                                       \
      for (int k = 0; k < 32; ++k) s += sG[e * 33 + k] * sG[lane * 33 + k];   \
      sc = s;                                                                 \
    }                                                                         \
    float mx = sc;                                                            \
    _Pragma("unroll")                                                         \
    for (int off = 32; off; off >>= 1) mx = fmaxf(mx, __shfl_xor(mx, off));   \
    float p = (lane < E_NODES) ? __expf(sc - mx) : 0.f;                       \
    float sum = p;                                                            \
    _Pragma("unroll")                                                         \
    for (int off = 32; off; off >>= 1) sum += __shfl_xor(sum, off);           \
    p = p / sum;                                                              \
    float v = (lane < E_NODES) ? p : -1.f;                                    \
    _Pragma("unroll 1")                                                       \
    for (int it = 0; it < TOPK; ++it) {                                       \
      float bv = v; int bi = lane;                                            \
      _Pragma("unroll")                                                       \
      for (int off = 32; off; off >>= 1) {                                    \
        const float ov = __shfl_xor(bv, off);                                 \
        const int   oi = __shfl_xor(bi, off);                                 \
        if (ov > bv || (ov == bv && oi < bi)) { bv = ov; bi = oi; }           \
      }                                                                       \
      if (lane == 0) { stv[e * 10 + it] = bv; sti[e * 10 + it] = bi; }        \
      if (lane == bi) v = -1.f;                                               \
    }                                                                         \
  }

#define GP_PHASE()                                                            \
  for (int e = wave; e < E_NODES; e += 8) {                                   \
    const float* hrow = sH + e * 65;                                          \
    const float* wp = sWt + lane;                                             \
    const float* wg = sWt + 64 + (lane & 31);                                 \
    float accp = 0.f, accg = 0.f;                                             \
    _Pragma("unroll 8")                                                       \
    for (int d = 0; d < 64; ++d) {                                            \
      const float h = hrow[d];                                                \
      accp += h * wp[d * 97];                                                 \
      accg += h * wg[d * 97];                                                 \
    }                                                                         \
    sP[e * 64 + lane] = accp;                                                 \
    if (lane < 32) sG[e * 33 + lane] = 1.f - 2.f / (__expf(2.f * accg) + 1.f);\
  }

  // ---- layer 1: topk + combine -> sH
  TOPK_PHASE();
  __syncthreads();
  for (int e = wave; e < E_NODES; e += 8) {
    float acc = gc1b[lane];
#pragma unroll
    for (int j = 0; j < TOPK; ++j)
      acc += stv[e * 10 + j] * sP[sti[e * 10 + j] * 64 + lane];
    sH[e * 65 + lane] = fmaxf(acc, 0.f);
  }
  __syncthreads();

  // ---- layer 2
  GP_PHASE();
  __syncthreads();
  for (int i = tid; i < 64 * 64; i += 512)
    sWt[(i & 63) * 97 + (i >> 6)] = gc3w[i];
  for (int i = tid; i < 32 * 64; i += 512)
    sWt[(i & 63) * 97 + 64 + (i >> 6)] = Wbn3[i];
  TOPK_PHASE();
  __syncthreads();
  for (int e = wave; e < E_NODES; e += 8) {
    float acc = gc2b[lane];
#pragma unroll
    for (int j = 0; j < TOPK; ++j)
      acc += stv[e * 10 + j] * sP[sti[e * 10 + j] * 64 + lane];
    sH[e * 65 + lane] = fmaxf(acc, 0.f);
  }
  __syncthreads();

  // ---- layer 3 + cls
  GP_PHASE();
  __syncthreads();
  TOPK_PHASE();
  __syncthreads();
  {
    float accn[4] = {0.f, 0.f, 0.f, 0.f};
    for (int e = wave; e < E_NODES; e += 8) {
      float acc = gc3b[lane];
#pragma unroll
      for (int j = 0; j < TOPK; ++j)
        acc += stv[e * 10 + j] * sP[sti[e * 10 + j] * 64 + lane];
      acc = fmaxf(acc, 0.f);
#pragma unroll
      for (int n = 0; n < 4; ++n)
        accn[n] += acc * cw[n * 3968 + e * 64 + lane];
    }
#pragma unroll
    for (int n = 0; n < 4; ++n) {
      float s = accn[n];
#pragma unroll
      for (int off = 32; off; off >>= 1) s += __shfl_xor(s, off);
      if (lane == 0) sred[wave * 4 + n] = s;
    }
    __syncthreads();
    if (tid < 4) {
      float s = cb[tid];
#pragma unroll
      for (int w = 0; w < 8; ++w) s += sred[w * 4 + tid];
      out[b * 4 + tid] = s;
    }
  }
#undef TOPK_PHASE
#undef GP_PHASE
}

// ================= launch =================
extern "C" void kernel_launch(void* const* d_in, const int* in_sizes, int n_in,
                              void* d_out, int out_size, void* d_ws, size_t ws_size,
                              hipStream_t stream) {
  const float* x    = (const float*)d_in[0];
  const float* c1w  = (const float*)d_in[1];
  const float* c1b  = (const float*)d_in[2];
  const float* c2w  = (const float*)d_in[3];
  const float* c2b  = (const float*)d_in[4];
  const float* c3w  = (const float*)d_in[5];
  const float* c3b  = (const float*)d_in[6];
  const float* Wbn1 = (const float*)d_in[7];
  const float* gc1w = (const float*)d_in[8];
  const float* gc1b = (const float*)d_in[9];
  const float* Wbn2 = (const float*)d_in[10];
  const float* gc2w = (const float*)d_in[11];
  const float* gc2b = (const float*)d_in[12];
  const float* Wbn3 = (const float*)d_in[13];
  const float* gc3w = (const float*)d_in[14];
  const float* gc3b = (const float*)d_in[15];
  const float* clsw = (const float*)d_in[16];
  const float* clsb = (const float*)d_in[17];
  float* out = (float*)d_out;

  float* wsf = (float*)d_ws;
  float* W2T = wsf;                         // 10240
  float* W3T = wsf + 10240;                 // 40960
  float* WT  = wsf + 51200;                 // 49152 (WT4 layout)
  float* GP  = wsf + 100352;                // 31744*96 = 3,047,424 (~12.6 MB)

  const int SOGC_BYTES = 17524 * 4;         // 70,096 B dynamic LDS

  (void)hipFuncSetAttribute((const void*)sogc_fused_kernel,
                            hipFuncAttributeMaxDynamicSharedMemorySize, SOGC_BYTES);

  wt_kernel<<<392, 256, 0, stream>>>(c2w, c3w, Wbn1, gc1w, W2T, W3T, WT);
  conv_chain_kernel<<<7936, 256, 0, stream>>>(x, c1w, c1b, W2T, c2b, W3T, c3b,
                                              WT, GP);
  sogc_fused_kernel<<<512, 512, SOGC_BYTES, stream>>>(
      GP, gc1b, Wbn2, gc2w, gc2b, Wbn3, gc3w, gc3b, clsw, clsb, out);
}

// Round 14
// 1005.715 us; speedup vs baseline: 2.2275x; 1.0174x over previous
//
#include <hip/hip_runtime.h>

#define E_NODES 62
#define TOPK 10
// conv geometry: (5,64) -> c1 5x5 -> (1,60) -> pool -> 30
//                -> c2 1x5 (64ch) -> 26 -> pool -> 13
//                -> c3 1x5 (128ch) -> 9 -> pool -> 4 (pos 8 unused)

// ---- weight reshape: w2t(160,64), w3t(320,128),
// WT4[d4][j][q] = (j<32 ? Wbn1[j][4*d4+q] : gc1w[j-32][4*d4+q])  (49152 fl)
__global__ __launch_bounds__(256) void wt_kernel(
    const float* __restrict__ w2, const float* __restrict__ w3,
    const float* __restrict__ Wbn1, const float* __restrict__ gc1w,
    float* __restrict__ w2t, float* __restrict__ w3t, float* __restrict__ wt)
{
  const int j = blockIdx.x * 256 + threadIdx.x;
  if (j < 10240) {
    const int r = j >> 6, o = j & 63;
    w2t[j] = w2[o * 160 + r];
  } else if (j < 51200) {
    const int k = j - 10240;               // < 40960
    const int r = k >> 7, o = k & 127;
    w3t[k] = w3[o * 320 + r];
  } else {
    const int k = j - 51200;               // < 49152
    const int d4 = k / 384, rem = k - d4 * 384;
    const int jj = rem >> 2, q = rem & 3;
    const int d = d4 * 4 + q;
    wt[k] = (jj < 32) ? Wbn1[jj * 512 + d] : gc1w[(jj - 32) * 512 + d];
  }
}

// async global->LDS, 16B/lane; n4 = count of float4; 256-thread stride
__device__ __forceinline__ void stage16(const float* __restrict__ g,
                                        float* l, int n4, int tid) {
  for (int i = tid; i < n4; i += 256)
    __builtin_amdgcn_global_load_lds(
        (const __attribute__((address_space(1))) void*)(g + 4 * i),
        (__attribute__((address_space(3))) void*)(l + 4 * i), 16, 0, 0);
}

// ================= fused conv chain + GP tail =================
// Verified round-9/10/13 structure (885 us, VGPR 84, no spill, 3 blocks/CU).
// r14 delta: conv1 weights staged at pitch 28 -> wr[25] preloaded via b128
// (per-thread weight ds_reads 400 -> 112). img alias moved to 9120.
__global__ __launch_bounds__(256, 3) void conv_chain_kernel(
    const float* __restrict__ x,
    const float* __restrict__ w1, const float* __restrict__ b1,
    const float* __restrict__ w2t, const float* __restrict__ b2,
    const float* __restrict__ w3t, const float* __restrict__ b3,
    const float* __restrict__ WT, float* __restrict__ GP)
{
  __shared__ float sm[13312];
  float* s_h1  = sm;            // 4*32*32 (pitch 32)
  float* s_h2  = sm + 4096;     // 4*64*16 (pitch 16)
  float* s_wa  = sm + 8192;     // 2560
  float* s_wb  = sm + 10752;    // 2560
  float* s_w1  = sm + 8192;     // conv1 w pitch-28 (896) + b (32) = 928, aliases wA
  float* s_img = sm + 9120;     // 1280, aliases wA (9120+1280=10400 < 10752)

  const int tid = threadIdx.x;
  const int n0 = blockIdx.x * 4;
  const int im = tid >> 6;
  const int lane = tid & 63;

  stage16(x + (size_t)n0 * 320, s_img, 320, tid);
  for (int i = tid; i < 832; i += 256) {
    if (i < 800) {
      const int row = i / 25, col = i - row * 25;
      s_w1[row * 28 + col] = w1[i];
    } else {
      s_w1[896 + (i - 800)] = b1[i - 800];
    }
  }
  __syncthreads();

  // stage conv2 chunk 0 -> wB during conv1 compute
  stage16(w2t, s_wb, 640, tid);

  // ---- conv1 + relu + pool. lane = (half, tp): stride-1 writes (no conflict)
  {
    const int tp = lane & 31;        // pooled position, 0..29 used
    const int half = lane >> 5;      // output-channel half
    if (tp < 30) {
      const float* ib = s_img + im * 320;
      const int t0 = 2 * tp;
      float r[5][6];
#pragma unroll
      for (int kr = 0; kr < 5; ++kr)
#pragma unroll
        for (int c = 0; c < 6; ++c) r[kr][c] = ib[kr * 64 + t0 + c];
#pragma unroll 4
      for (int oi = 0; oi < 16; ++oi) {
        const int o = half * 16 + oi;
        const float* w = s_w1 + o * 28;       // pitch 28: o*112B, 16B-aligned
        float wr[25];
#pragma unroll
        for (int q = 0; q < 6; ++q) {         // 6 b128 broadcast reads
          const float4 v = *(const float4*)(w + 4 * q);
          wr[4 * q] = v.x; wr[4 * q + 1] = v.y; wr[4 * q + 2] = v.z; wr[4 * q + 3] = v.w;
        }
        wr[24] = w[24];
        float s0 = s_w1[896 + o], s1 = s0;
#pragma unroll
        for (int kr = 0; kr < 5; ++kr) {
#pragma unroll
          for (int k = 0; k < 5; ++k) {       // pure v_fmac form
            const float wv = wr[kr * 5 + k];
            s0 += r[kr][k] * wv;
            s1 += r[kr][k + 1] * wv;
          }
        }
        s_h1[im * 1024 + o * 32 + tp] = fmaxf(fmaxf(s0, s1), 0.f);
      }
    }
  }
  __syncthreads();   // h1 ready; conv2 chunk0 staged (vmcnt drained)

  // ---- conv2 + relu + pool: thread = (im, o). T-TILED (7+6) for reg pressure.
  {
    const int o = lane;
    const float bia = b2[o];

    // tile 0: pooled t = 0..6 (inputs 0..17)
    {
      float acc0[7], acc1[7];
#pragma unroll
      for (int t = 0; t < 7; ++t) { acc0[t] = bia; acc1[t] = bia; }
#pragma unroll 1
      for (int c = 0; c < 4; ++c) {
        const float* rb = (c & 1) ? s_wa : s_wb;
        float*       nb = (c & 1) ? s_wb : s_wa;
        stage16(w2t + ((c < 3) ? (c + 1) * 2560 : 0), nb, 640, tid);
#pragma unroll 4
        for (int cl = 0; cl < 8; ++cl) {
          const float* hr = s_h1 + im * 1024 + (c * 8 + cl) * 32;  // broadcast
          float r[18];
#pragma unroll
          for (int q = 0; q < 4; ++q) {
            const float4 v = *(const float4*)(hr + q * 4);
            r[q * 4] = v.x; r[q * 4 + 1] = v.y; r[q * 4 + 2] = v.z; r[q * 4 + 3] = v.w;
          }
          { const float2 v = *(const float2*)(hr + 16); r[16] = v.x; r[17] = v.y; }
          const float* wb = rb + cl * 320 + o;         // (cl*5+k)*64+o, imm offsets
#pragma unroll
          for (int k = 0; k < 5; ++k) {
            const float wv = wb[k * 64];
#pragma unroll
            for (int t = 0; t < 7; ++t) {              // pure v_fmac
              acc0[t] += r[2 * t + k] * wv;
              acc1[t] += r[2 * t + 1 + k] * wv;
            }
          }
        }
        __syncthreads();    // next chunk staged + all reads of rb done
      }
#pragma unroll
      for (int t = 0; t < 7; ++t)
        s_h2[im * 1024 + o * 16 + t] = fmaxf(fmaxf(acc0[t], acc1[t]), 0.f);
    }

    // tile 1: pooled t = 7..12 (inputs 14..29; r[j] = input[12+j])
    {
      float acc0[6], acc1[6];
#pragma unroll
      for (int t = 0; t < 6; ++t) { acc0[t] = bia; acc1[t] = bia; }
#pragma unroll 1
      for (int c = 0; c < 4; ++c) {
        const float* rb = (c & 1) ? s_wa : s_wb;
        float*       nb = (c & 1) ? s_wb : s_wa;
        // next: tile1 chunk c+1, else conv3 chunk 0
        stage16((c < 3) ? (w2t + (c + 1) * 2560) : w3t, nb, 640, tid);
#pragma unroll 4
        for (int cl = 0; cl < 8; ++cl) {
          const float* hr = s_h1 + im * 1024 + (c * 8 + cl) * 32;
          float r[18];
#pragma unroll
          for (int q = 0; q < 4; ++q) {
            const float4 v = *(const float4*)(hr + 12 + q * 4);
            r[q * 4] = v.x; r[q * 4 + 1] = v.y; r[q * 4 + 2] = v.z; r[q * 4 + 3] = v.w;
          }
          { const float2 v = *(const float2*)(hr + 28); r[16] = v.x; r[17] = v.y; }
          const float* wb = rb + cl * 320 + o;
#pragma unroll
          for (int k = 0; k < 5; ++k) {
            const float wv = wb[k * 64];
#pragma unroll
            for (int t = 0; t < 6; ++t) {
              const int t0 = 2 * t + 2;                // input[2(t+7)] local
              acc0[t] += r[t0 + k] * wv;
              acc1[t] += r[t0 + 1 + k] * wv;
            }
          }
        }
        __syncthreads();
      }
#pragma unroll
      for (int t = 0; t < 6; ++t)
        s_h2[im * 1024 + o * 16 + 7 + t] = fmaxf(fmaxf(acc0[t], acc1[t]), 0.f);
    }
  }

  // stage WT slice 0 (3072 fl <= 4096 h1 zone); h1 dead after conv2.
  stage16(WT, s_h1, 768, tid);

  // ---- conv3 + relu + pool -> pooled h3 in wB zone. 2-oc tile (lane, lane+64).
  {
    const int oc = lane;
    float acc[2][8];
#pragma unroll
    for (int t = 0; t < 8; ++t) {
      acc[0][t] = b3[oc];
      acc[1][t] = b3[64 + oc];
    }
#pragma unroll 1
    for (int k = 0; k < 16; ++k) {
      const float* rb = (k & 1) ? s_wa : s_wb;
      float*       nb = (k & 1) ? s_wb : s_wa;
      if (k < 15) stage16(w3t + (k + 1) * 2560, nb, 640, tid);
#pragma unroll 2
      for (int cl = 0; cl < 4; ++cl) {
        const float* hr = s_h2 + im * 1024 + (k * 4 + cl) * 16;  // broadcast
        float r[12];
#pragma unroll
        for (int q = 0; q < 3; ++q) {
          const float4 v = *(const float4*)(hr + q * 4);
          r[q * 4] = v.x; r[q * 4 + 1] = v.y; r[q * 4 + 2] = v.z; r[q * 4 + 3] = v.w;
        }
        const float* wb = rb + cl * 640 + oc;          // (cl*5+kk)*128+oc
#pragma unroll
        for (int kk = 0; kk < 5; ++kk) {
          const float wv0 = wb[kk * 128];
          const float wv1 = wb[kk * 128 + 64];
#pragma unroll
          for (int t = 0; t < 8; ++t) {                // pure v_fmac
            acc[0][t] += r[t + kk] * wv0;
            acc[1][t] += r[t + kk] * wv1;
          }
        }
      }
      __syncthreads();
    }
    // pooled h3 (512/image) -> wB zone (free: last wB read is k=14)
    float* h3w = s_wb + im * 520;
    float4 ov;
    ov.x = fmaxf(fmaxf(acc[0][0], acc[0][1]), 0.f);
    ov.y = fmaxf(fmaxf(acc[0][2], acc[0][3]), 0.f);
    ov.z = fmaxf(fmaxf(acc[0][4], acc[0][5]), 0.f);
    ov.w = fmaxf(fmaxf(acc[0][6], acc[0][7]), 0.f);
    *(float4*)(h3w + oc * 4) = ov;
    ov.x = fmaxf(fmaxf(acc[1][0], acc[1][1]), 0.f);
    ov.y = fmaxf(fmaxf(acc[1][2], acc[1][3]), 0.f);
    ov.z = fmaxf(fmaxf(acc[1][4], acc[1][5]), 0.f);
    ov.w = fmaxf(fmaxf(acc[1][6], acc[1][7]), 0.f);
    *(float4*)(h3w + 256 + oc * 4) = ov;
  }

  // ---- GP tail: gp[j<32] = tanh(Wbn1.h), gp[32+o] = gc1w[o].h
  // 16 slices of 32 d (3072 fl); zone (s&1 ? h2 : h1); stage s+2 into zone
  // freed at barrier s. All reads ds_read_b128.
  {
    stage16(WT + 3072, s_h2, 768, tid);    // slice 1 (h2 dead post-conv3)
    __syncthreads();                       // h3 visible; slices 0,1 drained
    const float* h3 = s_wb + im * 520;
    const int jP = 32 + lane, jG = lane & 31;
    float accp = 0.f, accg = 0.f;
#pragma unroll 1
    for (int s = 0; s < 16; ++s) {
      const float* z = (s & 1) ? s_h2 : s_h1;
#pragma unroll
      for (int d4 = 0; d4 < 8; ++d4) {
        const float4 hv = *(const float4*)(h3 + s * 32 + d4 * 4);   // broadcast
        const float4 wp = *(const float4*)(z + d4 * 384 + jP * 4);  // b128
        const float4 wg = *(const float4*)(z + d4 * 384 + jG * 4);  // b128
        accp += hv.x * wp.x + hv.y * wp.y + hv.z * wp.z + hv.w * wp.w;
        accg += hv.x * wg.x + hv.y * wg.y + hv.z * wg.z + hv.w * wg.w;
      }
      __syncthreads();                               // zone reads done
      if (s < 14) stage16(WT + (s + 2) * 3072, (s & 1) ? s_h2 : s_h1, 768, tid);
    }
    float* gpo = GP + (size_t)(n0 + im) * 96;
    gpo[32 + lane] = accp;
    if (lane < 32) gpo[lane] = 1.f - 2.f / (__expf(2.f * accg) + 1.f);
  }
}

// ================= fused SOGC x3 + classifier =================
// One block (1024 thr = 16 waves) per batch element b; e-rows strided by 16.
__global__ __launch_bounds__(1024, 2) void sogc_fused_kernel(
    const float* __restrict__ GP,   const float* __restrict__ gc1b,
    const float* __restrict__ Wbn2, const float* __restrict__ gc2w,
    const float* __restrict__ gc2b,
    const float* __restrict__ Wbn3, const float* __restrict__ gc3w,
    const float* __restrict__ gc3b,
    const float* __restrict__ cw,   const float* __restrict__ cb,
    float* __restrict__ out)
{
  extern __shared__ float sm[];
  float* sH  = sm;                 // 62*65 = 4030
  float* sWt = sm + 4030;          // 64*97 = 6208
  float* sG  = sm + 10238;         // 62*33 = 2046
  float* sP  = sm + 12284;         // 62*64 = 3968
  float* stv = sm + 16252;         // 620
  int*   sti = (int*)(sm + 16872); // 620
  float* sred = sm + 17492;        // 64 (16 waves x 4)

  const int b = blockIdx.x, tid = threadIdx.x;
  const int lane = tid & 63, wave = tid >> 6;   // wave in [0,16)

  const float* gp = GP + (size_t)b * 62 * 96;
  for (int i = tid; i < 62 * 96; i += 1024) {
    const int e = i / 96, q = i - e * 96;
    const float v = gp[i];
    if (q < 32) sG[e * 33 + q] = v; else sP[e * 64 + (q - 32)] = v;
  }
  for (int i = tid; i < 64 * 64; i += 1024)       // gc2w (o,d) -> sWt[d][o]
    sWt[(i & 63) * 97 + (i >> 6)] = gc2w[i];
  for (int i = tid; i < 32 * 64; i += 1024)       // Wbn2 (k,d) -> sWt[d][64+k]
    sWt[(i & 63) * 97 + 64 + (i >> 6)] = Wbn2[i];
  __syncthreads();

#define TOPK_PHASE()                                                          \
  for (int e = wave; e < E_NODES; e += 16) {                                  \
    float sc = -1e30f;                                                        \
    if (lane < E_NODES) {                                                     \
      float s = 0.f;                                                          \
      _Pragma("unroll")                                                       \
      for (int k = 0; k < 32; ++k) s += sG[e * 33 + k] * sG[lane * 33 + k];   \
      sc = s;                                                                 \
    }                                                                         \
    float mx = sc;                                                            \
    _Pragma("unroll")                                                         \
    for (int off = 32; off; off >>= 1) mx = fmaxf(mx, __shfl_xor(mx, off));   \
    float p = (lane < E_NODES) ? __expf(sc - mx) : 0.f;                       \
    float sum = p;                                                            \
    _Pragma("unroll")                                                         \
    for (int off = 32; off; off >>= 1) sum += __shfl_xor(sum, off);           \
    p = p / sum;                                                              \
    float v = (lane < E_NODES) ? p : -1.f;                                    \
    _Pragma("unroll 1")                                                       \
    for (int it = 0; it < TOPK; ++it) {                                       \
      float bv = v; int bi = lane;                                            \
      _Pragma("unroll")                                                       \
      for (int off = 32; off; off >>= 1) {                                    \
        const float ov = __shfl_xor(bv, off);                                 \
        const int   oi = __shfl_xor(bi, off);                                 \
        if (ov > bv || (ov == bv && oi < bi)) { bv = ov; bi = oi; }           \
      }                                                                       \
      if (lane == 0) { stv[e * 10 + it] = bv; sti[e * 10 + it] = bi; }        \
      if (lane == bi) v = -1.f;                                               \
    }                                                                         \
  }

#define GP_PHASE()                                                            \
  for (int e = wave; e < E_NODES; e += 16) {                                  \
    const float* hrow = sH + e * 65;                                          \
    const float* wp = sWt + lane;                                             \
    const float* wg = sWt + 64 + (lane & 31);                                 \
    float accp = 0.f, accg = 0.f;                                             \
    _Pragma("unroll 8")                                                       \
    for (int d = 0; d < 64; ++d) {                                            \
      const float h = hrow[d];                                                \
      accp += h * wp[d * 97];                                                 \
      accg += h * wg[d * 97];                                                 \
    }                                                                         \
    sP[e * 64 + lane] = accp;                                                 \
    if (lane < 32) sG[e * 33 + lane] = 1.f - 2.f / (__expf(2.f * accg) + 1.f);\
  }

  // ---- layer 1: topk + combine -> sH
  TOPK_PHASE();
  __syncthreads();
  for (int e = wave; e < E_NODES; e += 16) {
    float acc = gc1b[lane];
#pragma unroll
    for (int j = 0; j < TOPK; ++j)
      acc += stv[e * 10 + j] * sP[sti[e * 10 + j] * 64 + lane];
    sH[e * 65 + lane] = fmaxf(acc, 0.f);
  }
  __syncthreads();

  // ---- layer 2
  GP_PHASE();
  __syncthreads();
  for (int i = tid; i < 64 * 64; i += 1024)
    sWt[(i & 63) * 97 + (i >> 6)] = gc3w[i];
  for (int i = tid; i < 32 * 64; i += 1024)
    sWt[(i & 63) * 97 + 64 + (i >> 6)] = Wbn3[i];
  TOPK_PHASE();
  __syncthreads();
  for (int e = wave; e < E_NODES; e += 16) {
    float acc = gc2b[lane];
#pragma unroll
    for (int j = 0; j < TOPK; ++j)
      acc += stv[e * 10 + j] * sP[sti[e * 10 + j] * 64 + lane];
    sH[e * 65 + lane] = fmaxf(acc, 0.f);
  }
  __syncthreads();

  // ---- layer 3 + cls
  GP_PHASE();
  __syncthreads();
  TOPK_PHASE();
  __syncthreads();
  {
    float accn[4] = {0.f, 0.f, 0.f, 0.f};
    for (int e = wave; e < E_NODES; e += 16) {
      float acc = gc3b[lane];
#pragma unroll
      for (int j = 0; j < TOPK; ++j)
        acc += stv[e * 10 + j] * sP[sti[e * 10 + j] * 64 + lane];
      acc = fmaxf(acc, 0.f);
#pragma unroll
      for (int n = 0; n < 4; ++n)
        accn[n] += acc * cw[n * 3968 + e * 64 + lane];
    }
#pragma unroll
    for (int n = 0; n < 4; ++n) {
      float s = accn[n];
#pragma unroll
      for (int off = 32; off; off >>= 1) s += __shfl_xor(s, off);
      if (lane == 0) sred[wave * 4 + n] = s;
    }
    __syncthreads();
    if (tid < 4) {
      float s = cb[tid];
#pragma unroll
      for (int w = 0; w < 16; ++w) s += sred[w * 4 + tid];
      out[b * 4 + tid] = s;
    }
  }
#undef TOPK_PHASE
#undef GP_PHASE
}

// ================= launch =================
extern "C" void kernel_launch(void* const* d_in, const int* in_sizes, int n_in,
                              void* d_out, int out_size, void* d_ws, size_t ws_size,
                              hipStream_t stream) {
  const float* x    = (const float*)d_in[0];
  const float* c1w  = (const float*)d_in[1];
  const float* c1b  = (const float*)d_in[2];
  const float* c2w  = (const float*)d_in[3];
  const float* c2b  = (const float*)d_in[4];
  const float* c3w  = (const float*)d_in[5];
  const float* c3b  = (const float*)d_in[6];
  const float* Wbn1 = (const float*)d_in[7];
  const float* gc1w = (const float*)d_in[8];
  const float* gc1b = (const float*)d_in[9];
  const float* Wbn2 = (const float*)d_in[10];
  const float* gc2w = (const float*)d_in[11];
  const float* gc2b = (const float*)d_in[12];
  const float* Wbn3 = (const float*)d_in[13];
  const float* gc3w = (const float*)d_in[14];
  const float* gc3b = (const float*)d_in[15];
  const float* clsw = (const float*)d_in[16];
  const float* clsb = (const float*)d_in[17];
  float* out = (float*)d_out;

  float* wsf = (float*)d_ws;
  float* W2T = wsf;                         // 10240
  float* W3T = wsf + 10240;                 // 40960
  float* WT  = wsf + 51200;                 // 49152 (WT4 layout)
  float* GP  = wsf + 100352;                // 31744*96 = 3,047,424 (~12.6 MB)

  const int SOGC_BYTES = 17556 * 4;         // 70,224 B dynamic LDS

  (void)hipFuncSetAttribute((const void*)sogc_fused_kernel,
                            hipFuncAttributeMaxDynamicSharedMemorySize, SOGC_BYTES);

  wt_kernel<<<392, 256, 0, stream>>>(c2w, c3w, Wbn1, gc1w, W2T, W3T, WT);
  conv_chain_kernel<<<7936, 256, 0, stream>>>(x, c1w, c1b, W2T, c2b, W3T, c3b,
                                              WT, GP);
  sogc_fused_kernel<<<512, 1024, SOGC_BYTES, stream>>>(
      GP, gc1b, Wbn2, gc2w, gc2b, Wbn3, gc3w, gc3b, clsw, clsb, out);
}

// Round 15
// 952.704 us; speedup vs baseline: 2.3514x; 1.0556x over previous
//
#include <hip/hip_runtime.h>

#define E_NODES 62
#define TOPK 10
// conv geometry: (5,64) -> c1 5x5 -> (1,60) -> pool -> 30
//                -> c2 1x5 (64ch) -> 26 -> pool -> 13
//                -> c3 1x5 (128ch) -> 9 -> pool -> 4 (pos 8 unused)

// ---- weight reshape: w2t(160,64), w3t(320,128),
// WT4[d4][j][q] = (j<32 ? Wbn1[j][4*d4+q] : gc1w[j-32][4*d4+q])  (49152 fl)
__global__ __launch_bounds__(256) void wt_kernel(
    const float* __restrict__ w2, const float* __restrict__ w3,
    const float* __restrict__ Wbn1, const float* __restrict__ gc1w,
    float* __restrict__ w2t, float* __restrict__ w3t, float* __restrict__ wt)
{
  const int j = blockIdx.x * 256 + threadIdx.x;
  if (j < 10240) {
    const int r = j >> 6, o = j & 63;
    w2t[j] = w2[o * 160 + r];
  } else if (j < 51200) {
    const int k = j - 10240;               // < 40960
    const int r = k >> 7, o = k & 127;
    w3t[k] = w3[o * 320 + r];
  } else {
    const int k = j - 51200;               // < 49152
    const int d4 = k / 384, rem = k - d4 * 384;
    const int jj = rem >> 2, q = rem & 3;
    const int d = d4 * 4 + q;
    wt[k] = (jj < 32) ? Wbn1[jj * 512 + d] : gc1w[(jj - 32) * 512 + d];
  }
}

// async global->LDS, 16B/lane; n4 = count of float4; 256-thread stride
__device__ __forceinline__ void stage16(const float* __restrict__ g,
                                        float* l, int n4, int tid) {
  for (int i = tid; i < n4; i += 256)
    __builtin_amdgcn_global_load_lds(
        (const __attribute__((address_space(1))) void*)(g + 4 * i),
        (__attribute__((address_space(3))) void*)(l + 4 * i), 16, 0, 0);
}

// ================= fused conv chain + GP tail =================
// r15: LDS diet 53248 -> 39936 B for 4 blocks/CU (16 waves/CU, +33% TLP).
// h1 pitch 30 (3840 fl), h2 pitch 14 (3584 fl), weight chunks 1280 fl
// (conv2 = 4 ci, conv3 = 2 ci); img+w1 alias the h2 zone during conv1.
// __launch_bounds__(256,4): 16 waves/CU -> VGPR cap 128; natural ~84 fits.
// Layout (floats): h1@0 (3840) | h2@3840 (3584) | wA@7424 (1280) | wB@8704 (1280)
//   img -> h2 zone @3840 (1280); w1 pitch-28 -> @5120 (928)
//   GP tail: WT 32-d slices (3072 fl) dbuf h1/h2 zones; h3[4][520] @7424 (2080)
__global__ __launch_bounds__(256, 4) void conv_chain_kernel(
    const float* __restrict__ x,
    const float* __restrict__ w1, const float* __restrict__ b1,
    const float* __restrict__ w2t, const float* __restrict__ b2,
    const float* __restrict__ w3t, const float* __restrict__ b3,
    const float* __restrict__ WT, float* __restrict__ GP)
{
  __shared__ float sm[9984];
  float* s_h1  = sm;            // [4][32][30]
  float* s_h2  = sm + 3840;     // [4][64][14]
  float* s_wa  = sm + 7424;     // 1280
  float* s_wb  = sm + 8704;     // 1280
  float* s_img = sm + 3840;     // [4][320] aliases h2 zone (conv1 only)
  float* s_w1  = sm + 5120;     // w pitch-28 (896) + b (32), h2 zone (conv1 only)
  float* s_h3  = sm + 7424;     // [4][520] aliases wA+wB (GP tail)

  const int tid = threadIdx.x;
  const int n0 = blockIdx.x * 4;
  const int im = tid >> 6;
  const int lane = tid & 63;

  stage16(x + (size_t)n0 * 320, s_img, 320, tid);
  for (int i = tid; i < 832; i += 256) {
    if (i < 800) {
      const int row = i / 25, col = i - row * 25;
      s_w1[row * 28 + col] = w1[i];
    } else {
      s_w1[896 + (i - 800)] = b1[i - 800];
    }
  }
  __syncthreads();

  // stage conv2 chunk 0 (4 ci = 1280 fl) -> wB during conv1 compute
  stage16(w2t, s_wb, 320, tid);

  // ---- conv1 + relu + pool. lane = (half, tp): stride-1 writes;
  // half alias offset 480 fl == 0 mod 32 -> 2-way (free).
  {
    const int tp = lane & 31;        // pooled position, 0..29 used
    const int half = lane >> 5;      // output-channel half
    if (tp < 30) {
      const float* ib = s_img + im * 320;
      const int t0 = 2 * tp;
      float r[5][6];
#pragma unroll
      for (int kr = 0; kr < 5; ++kr)
#pragma unroll
        for (int c = 0; c < 6; ++c) r[kr][c] = ib[kr * 64 + t0 + c];
#pragma unroll 4
      for (int oi = 0; oi < 16; ++oi) {
        const int o = half * 16 + oi;
        const float* w = s_w1 + o * 28;       // pitch 28, 16B-aligned rows
        float wr[25];
#pragma unroll
        for (int q = 0; q < 6; ++q) {         // b128 broadcast reads
          const float4 v = *(const float4*)(w + 4 * q);
          wr[4 * q] = v.x; wr[4 * q + 1] = v.y; wr[4 * q + 2] = v.z; wr[4 * q + 3] = v.w;
        }
        wr[24] = w[24];
        float s0 = s_w1[896 + o], s1 = s0;
#pragma unroll
        for (int kr = 0; kr < 5; ++kr) {
#pragma unroll
          for (int k = 0; k < 5; ++k) {       // pure v_fmac form
            const float wv = wr[kr * 5 + k];
            s0 += r[kr][k] * wv;
            s1 += r[kr][k + 1] * wv;
          }
        }
        s_h1[im * 960 + o * 30 + tp] = fmaxf(fmaxf(s0, s1), 0.f);
      }
    }
  }
  __syncthreads();   // h1 ready; conv2 chunk0 staged (vmcnt drained)

  // ---- conv2 + relu + pool: thread = (im, o). T-TILED (7+6); 8 chunks x 4 ci.
  {
    const int o = lane;
    const float bia = b2[o];

    // tile 0: pooled t = 0..6 (inputs 0..17)
    {
      float acc0[7], acc1[7];
#pragma unroll
      for (int t = 0; t < 7; ++t) { acc0[t] = bia; acc1[t] = bia; }
#pragma unroll 1
      for (int c = 0; c < 8; ++c) {
        const float* rb = (c & 1) ? s_wa : s_wb;
        float*       nb = (c & 1) ? s_wb : s_wa;
        stage16(w2t + ((c < 7) ? (c + 1) * 1280 : 0), nb, 320, tid);
#pragma unroll
        for (int cl = 0; cl < 4; ++cl) {
          const float* hr = s_h1 + im * 960 + (c * 4 + cl) * 30;  // broadcast
          float r[18];
#pragma unroll
          for (int q = 0; q < 9; ++q) {                 // 8B-aligned float2
            const float2 v = *(const float2*)(hr + 2 * q);
            r[2 * q] = v.x; r[2 * q + 1] = v.y;
          }
          const float* wb = rb + cl * 320 + o;          // (cl*5+k)*64+o
#pragma unroll
          for (int k = 0; k < 5; ++k) {
            const float wv = wb[k * 64];
#pragma unroll
            for (int t = 0; t < 7; ++t) {               // pure v_fmac
              acc0[t] += r[2 * t + k] * wv;
              acc1[t] += r[2 * t + 1 + k] * wv;
            }
          }
        }
        __syncthreads();    // next chunk staged + all reads of rb done
      }
#pragma unroll
      for (int t = 0; t < 7; ++t)
        s_h2[im * 896 + o * 14 + t] = fmaxf(fmaxf(acc0[t], acc1[t]), 0.f);
    }

    // tile 1: pooled t = 7..12 (inputs 14..29; r[j] = input[12+j])
    {
      float acc0[6], acc1[6];
#pragma unroll
      for (int t = 0; t < 6; ++t) { acc0[t] = bia; acc1[t] = bia; }
#pragma unroll 1
      for (int c = 0; c < 8; ++c) {
        const float* rb = (c & 1) ? s_wa : s_wb;
        float*       nb = (c & 1) ? s_wb : s_wa;
        // next: tile1 chunk c+1, else conv3 chunk 0
        stage16((c < 7) ? (w2t + (c + 1) * 1280) : w3t, nb, 320, tid);
#pragma unroll
        for (int cl = 0; cl < 4; ++cl) {
          const float* hr = s_h1 + im * 960 + (c * 4 + cl) * 30;
          float r[18];
#pragma unroll
          for (int q = 0; q < 9; ++q) {                 // hr+12 stays 8B-aligned
            const float2 v = *(const float2*)(hr + 12 + 2 * q);
            r[2 * q] = v.x; r[2 * q + 1] = v.y;
          }
          const float* wb = rb + cl * 320 + o;
#pragma unroll
          for (int k = 0; k < 5; ++k) {
            const float wv = wb[k * 64];
#pragma unroll
            for (int t = 0; t < 6; ++t) {
              const int t0 = 2 * t + 2;                 // input[2(t+7)] local
              acc0[t] += r[t0 + k] * wv;
              acc1[t] += r[t0 + 1 + k] * wv;
            }
          }
        }
        __syncthreads();
      }
#pragma unroll
      for (int t = 0; t < 6; ++t)
        s_h2[im * 896 + o * 14 + 7 + t] = fmaxf(fmaxf(acc0[t], acc1[t]), 0.f);
    }
  }

  // stage WT slice 0 (3072 fl <= 3840 h1 zone); h1 dead after conv2.
  stage16(WT, s_h1, 768, tid);

  // ---- conv3 + relu + pool. 2-oc tile (lane, lane+64); 32 chunks x 2 ci.
  {
    const int oc = lane;
    float acc[2][8];
#pragma unroll
    for (int t = 0; t < 8; ++t) {
      acc[0][t] = b3[oc];
      acc[1][t] = b3[64 + oc];
    }
#pragma unroll 1
    for (int k = 0; k < 32; ++k) {
      const float* rb = (k & 1) ? s_wa : s_wb;
      float*       nb = (k & 1) ? s_wb : s_wa;
      if (k < 31) stage16(w3t + (k + 1) * 1280, nb, 320, tid);
#pragma unroll
      for (int cl = 0; cl < 2; ++cl) {
        const float* hr = s_h2 + im * 896 + (k * 2 + cl) * 14;  // broadcast
        float r[12];
#pragma unroll
        for (int q = 0; q < 6; ++q) {                   // 8B-aligned float2
          const float2 v = *(const float2*)(hr + 2 * q);
          r[2 * q] = v.x; r[2 * q + 1] = v.y;
        }
        const float* wb = rb + cl * 640 + oc;           // (cl*5+kk)*128+oc
#pragma unroll
        for (int kk = 0; kk < 5; ++kk) {
          const float wv0 = wb[kk * 128];
          const float wv1 = wb[kk * 128 + 64];
#pragma unroll
          for (int t = 0; t < 8; ++t) {                 // pure v_fmac
            acc[0][t] += r[t + kk] * wv0;
            acc[1][t] += r[t + kk] * wv1;
          }
        }
      }
      __syncthreads();
    }
    // pooled h3 (512/image, pitch 520) -> wA+wB zone (weights dead)
    float* h3w = s_h3 + im * 520;
    float4 ov;
    ov.x = fmaxf(fmaxf(acc[0][0], acc[0][1]), 0.f);
    ov.y = fmaxf(fmaxf(acc[0][2], acc[0][3]), 0.f);
    ov.z = fmaxf(fmaxf(acc[0][4], acc[0][5]), 0.f);
    ov.w = fmaxf(fmaxf(acc[0][6], acc[0][7]), 0.f);
    *(float4*)(h3w + oc * 4) = ov;
    ov.x = fmaxf(fmaxf(acc[1][0], acc[1][1]), 0.f);
    ov.y = fmaxf(fmaxf(acc[1][2], acc[1][3]), 0.f);
    ov.z = fmaxf(fmaxf(acc[1][4], acc[1][5]), 0.f);
    ov.w = fmaxf(fmaxf(acc[1][6], acc[1][7]), 0.f);
    *(float4*)(h3w + 256 + oc * 4) = ov;
  }

  // ---- GP tail: gp[j<32] = tanh(Wbn1.h), gp[32+o] = gc1w[o].h
  // 16 slices of 32 d (3072 fl); zone (s&1 ? h2 : h1); stage s+2 into zone
  // freed at barrier s. All reads ds_read_b128.
  {
    stage16(WT + 3072, s_h2, 768, tid);    // slice 1 (h2 dead post-conv3)
    __syncthreads();                       // h3 visible; slices 0,1 drained
    const float* h3 = s_h3 + im * 520;
    const int jP = 32 + lane, jG = lane & 31;
    float accp = 0.f, accg = 0.f;
#pragma unroll 1
    for (int s = 0; s < 16; ++s) {
      const float* z = (s & 1) ? s_h2 : s_h1;
#pragma unroll
      for (int d4 = 0; d4 < 8; ++d4) {
        const float4 hv = *(const float4*)(h3 + s * 32 + d4 * 4);   // broadcast
        const float4 wp = *(const float4*)(z + d4 * 384 + jP * 4);  // b128
        const float4 wg = *(const float4*)(z + d4 * 384 + jG * 4);  // b128
        accp += hv.x * wp.x + hv.y * wp.y + hv.z * wp.z + hv.w * wp.w;
        accg += hv.x * wg.x + hv.y * wg.y + hv.z * wg.z + hv.w * wg.w;
      }
      __syncthreads();                               // zone reads done
      if (s < 14) stage16(WT + (s + 2) * 3072, (s & 1) ? s_h2 : s_h1, 768, tid);
    }
    float* gpo = GP + (size_t)(n0 + im) * 96;
    gpo[32 + lane] = accp;
    if (lane < 32) gpo[lane] = 1.f - 2.f / (__expf(2.f * accg) + 1.f);
  }
}

// ================= fused SOGC x3 + classifier =================
// One block (1024 thr = 16 waves) per batch element b; e-rows strided by 16.
__global__ __launch_bounds__(1024, 2) void sogc_fused_kernel(
    const float* __restrict__ GP,   const float* __restrict__ gc1b,
    const float* __restrict__ Wbn2, const float* __restrict__ gc2w,
    const float* __restrict__ gc2b,
    const float* __restrict__ Wbn3, const float* __restrict__ gc3w,
    const float* __restrict__ gc3b,
    const float* __restrict__ cw,   const float* __restrict__ cb,
    float* __restrict__ out)
{
  extern __shared__ float sm[];
  float* sH  = sm;                 // 62*65 = 4030
  float* sWt = sm + 4030;          // 64*97 = 6208
  float* sG  = sm + 10238;         // 62*33 = 2046
  float* sP  = sm + 12284;         // 62*64 = 3968
  float* stv = sm + 16252;         // 620
  int*   sti = (int*)(sm + 16872); // 620
  float* sred = sm + 17492;        // 64 (16 waves x 4)

  const int b = blockIdx.x, tid = threadIdx.x;
  const int lane = tid & 63, wave = tid >> 6;   // wave in [0,16)

  const float* gp = GP + (size_t)b * 62 * 96;
  for (int i = tid; i < 62 * 96; i += 1024) {
    const int e = i / 96, q = i - e * 96;
    const float v = gp[i];
    if (q < 32) sG[e * 33 + q] = v; else sP[e * 64 + (q - 32)] = v;
  }
  for (int i = tid; i < 64 * 64; i += 1024)       // gc2w (o,d) -> sWt[d][o]
    sWt[(i & 63) * 97 + (i >> 6)] = gc2w[i];
  for (int i = tid; i < 32 * 64; i += 1024)       // Wbn2 (k,d) -> sWt[d][64+k]
    sWt[(i & 63) * 97 + 64 + (i >> 6)] = Wbn2[i];
  __syncthreads();

#define TOPK_PHASE()                                                          \
  for (int e = wave; e < E_NODES; e += 16) {                                  \
    float sc = -1e30f;                                                        \
    if (lane < E_NODES) {                                                     \
      float s = 0.f;                                                          \
      _Pragma("unroll")                                                       \
      for (int k = 0; k < 32; ++k) s += sG[e * 33 + k] * sG[lane * 33 + k];   \
      sc = s;                                                                 \
    }                                                                         \
    float mx = sc;                                                            \
    _Pragma("unroll")                                                         \
    for (int off = 32; off; off >>= 1) mx = fmaxf(mx, __shfl_xor(mx, off));   \
    float p = (lane < E_NODES) ? __expf(sc - mx) : 0.f;                       \
    float sum = p;                                                            \
    _Pragma("unroll")                                                         \
    for (int off = 32; off; off >>= 1) sum += __shfl_xor(sum, off);           \
    p = p / sum;                                                              \
    float v = (lane < E_NODES) ? p : -1.f;                                    \
    _Pragma("unroll 1")                                                       \
    for (int it = 0; it < TOPK; ++it) {                                       \
      float bv = v; int bi = lane;                                            \
      _Pragma("unroll")                                                       \
      for (int off = 32; off; off >>= 1) {                                    \
        const float ov = __shfl_xor(bv, off);                                 \
        const int   oi = __shfl_xor(bi, off);                                 \
        if (ov > bv || (ov == bv && oi < bi)) { bv = ov; bi = oi; }           \
      }                                                                       \
      if (lane == 0) { stv[e * 10 + it] = bv; sti[e * 10 + it] = bi; }        \
      if (lane == bi) v = -1.f;                                               \
    }                                                                         \
  }

#define GP_PHASE()                                                            \
  for (int e = wave; e < E_NODES; e += 16) {                                  \
    const float* hrow = sH + e * 65;                                          \
    const float* wp = sWt + lane;                                             \
    const float* wg = sWt + 64 + (lane & 31);                                 \
    float accp = 0.f, accg = 0.f;                                             \
    _Pragma("unroll 8")                                                       \
    for (int d = 0; d < 64; ++d) {                                            \
      const float h = hrow[d];                                                \
      accp += h * wp[d * 97];                                                 \
      accg += h * wg[d * 97];                                                 \
    }                                                                         \
    sP[e * 64 + lane] = accp;                                                 \
    if (lane < 32) sG[e * 33 + lane] = 1.f - 2.f / (__expf(2.f * accg) + 1.f);\
  }

  // ---- layer 1: topk + combine -> sH
  TOPK_PHASE();
  __syncthreads();
  for (int e = wave; e < E_NODES; e += 16) {
    float acc = gc1b[lane];
#pragma unroll
    for (int j = 0; j < TOPK; ++j)
      acc += stv[e * 10 + j] * sP[sti[e * 10 + j] * 64 + lane];
    sH[e * 65 + lane] = fmaxf(acc, 0.f);
  }
  __syncthreads();

  // ---- layer 2
  GP_PHASE();
  __syncthreads();
  for (int i = tid; i < 64 * 64; i += 1024)
    sWt[(i & 63) * 97 + (i >> 6)] = gc3w[i];
  for (int i = tid; i < 32 * 64; i += 1024)
    sWt[(i & 63) * 97 + 64 + (i >> 6)] = Wbn3[i];
  TOPK_PHASE();
  __syncthreads();
  for (int e = wave; e < E_NODES; e += 16) {
    float acc = gc2b[lane];
#pragma unroll
    for (int j = 0; j < TOPK; ++j)
      acc += stv[e * 10 + j] * sP[sti[e * 10 + j] * 64 + lane];
    sH[e * 65 + lane] = fmaxf(acc, 0.f);
  }
  __syncthreads();

  // ---- layer 3 + cls
  GP_PHASE();
  __syncthreads();
  TOPK_PHASE();
  __syncthreads();
  {
    float accn[4] = {0.f, 0.f, 0.f, 0.f};
    for (int e = wave; e < E_NODES; e += 16) {
      float acc = gc3b[lane];
#pragma unroll
      for (int j = 0; j < TOPK; ++j)
        acc += stv[e * 10 + j] * sP[sti[e * 10 + j] * 64 + lane];
      acc = fmaxf(acc, 0.f);
#pragma unroll
      for (int n = 0; n < 4; ++n)
        accn[n] += acc * cw[n * 3968 + e * 64 + lane];
    }
#pragma unroll
    for (int n = 0; n < 4; ++n) {
      float s = accn[n];
#pragma unroll
      for (int off = 32; off; off >>= 1) s += __shfl_xor(s, off);
      if (lane == 0) sred[wave * 4 + n] = s;
    }
    __syncthreads();
    if (tid < 4) {
      float s = cb[tid];
#pragma unroll
      for (int w = 0; w < 16; ++w) s += sred[w * 4 + tid];
      out[b * 4 + tid] = s;
    }
  }
#undef TOPK_PHASE
#undef GP_PHASE
}

// ================= launch =================
extern "C" void kernel_launch(void* const* d_in, const int* in_sizes, int n_in,
                              void* d_out, int out_size, void* d_ws, size_t ws_size,
                              hipStream_t stream) {
  const float* x    = (const float*)d_in[0];
  const float* c1w  = (const float*)d_in[1];
  const float* c1b  = (const float*)d_in[2];
  const float* c2w  = (const float*)d_in[3];
  const float* c2b  = (const float*)d_in[4];
  const float* c3w  = (const float*)d_in[5];
  const float* c3b  = (const float*)d_in[6];
  const float* Wbn1 = (const float*)d_in[7];
  const float* gc1w = (const float*)d_in[8];
  const float* gc1b = (const float*)d_in[9];
  const float* Wbn2 = (const float*)d_in[10];
  const float* gc2w = (const float*)d_in[11];
  const float* gc2b = (const float*)d_in[12];
  const float* Wbn3 = (const float*)d_in[13];
  const float* gc3w = (const float*)d_in[14];
  const float* gc3b = (const float*)d_in[15];
  const float* clsw = (const float*)d_in[16];
  const float* clsb = (const float*)d_in[17];
  float* out = (float*)d_out;

  float* wsf = (float*)d_ws;
  float* W2T = wsf;                         // 10240
  float* W3T = wsf + 10240;                 // 40960
  float* WT  = wsf + 51200;                 // 49152 (WT4 layout)
  float* GP  = wsf + 100352;                // 31744*96 = 3,047,424 (~12.6 MB)

  const int SOGC_BYTES = 17556 * 4;         // 70,224 B dynamic LDS

  (void)hipFuncSetAttribute((const void*)sogc_fused_kernel,
                            hipFuncAttributeMaxDynamicSharedMemorySize, SOGC_BYTES);

  wt_kernel<<<392, 256, 0, stream>>>(c2w, c3w, Wbn1, gc1w, W2T, W3T, WT);
  conv_chain_kernel<<<7936, 256, 0, stream>>>(x, c1w, c1b, W2T, c2b, W3T, c3b,
                                              WT, GP);
  sogc_fused_kernel<<<512, 1024, SOGC_BYTES, stream>>>(
      GP, gc1b, Wbn2, gc2w, gc2b, Wbn3, gc3w, gc3b, clsw, clsb, out);
}